// Round 5
// baseline (10351.630 us; speedup 1.0000x reference)
//
#include <hip/hip_runtime.h>
#include <math.h>

#define NB 4
#define NPTS 4096
#define SS 1024
#define KS 32
#define DIN 64
#define CC 128

// ws layout (bytes) — per-batch reuse keeps total < 66 MB
#define WS_NX   0                        // float[4*1024*3]
#define WS_GIDX 49152                    // int[4*1024*32]
#define WS_P    (1u<<20)                 // float[32768*128]  (one batch)
#define WS_Q    (WS_P + 16777216u)
#define WS_K    (WS_Q + 16777216u)
#define WS_V    (WS_K + 16777216u)       // end = 1MB + 64MB

// ---------------- FPS: 1 block per batch, exact-match arithmetic ----------------
__global__ __launch_bounds__(256) void fps_kernel(const float* __restrict__ xyz,
                                                  float* __restrict__ out_newxyz,
                                                  float* __restrict__ ws_nx) {
    int b = blockIdx.x;
    const float* xb = xyz + b * 3 * NPTS;
    __shared__ float xs[NPTS], ys[NPTS], zs[NPTS];
    __shared__ float redv[4];
    __shared__ int   redi[4];
    __shared__ int   bcast;
    int t = threadIdx.x;
    for (int n = t; n < NPTS; n += 256) {
        xs[n] = xb[n]; ys[n] = xb[NPTS + n]; zs[n] = xb[2 * NPTS + n];
    }
    __syncthreads();
    float dist[16];
#pragma unroll
    for (int j = 0; j < 16; ++j) dist[j] = 1e10f;
    int far = 0;
    for (int i = 0; i < SS; ++i) {
        float cx = xs[far], cy = ys[far], cz = zs[far];
        if (t == 0) {
            out_newxyz[b * 3 * SS + 0 * SS + i] = cx;
            out_newxyz[b * 3 * SS + 1 * SS + i] = cy;
            out_newxyz[b * 3 * SS + 2 * SS + i] = cz;
            ws_nx[(b * SS + i) * 3 + 0] = cx;
            ws_nx[(b * SS + i) * 3 + 1] = cy;
            ws_nx[(b * SS + i) * 3 + 2] = cz;
        }
        float bestv = -1.0f; int bestn = 0;
#pragma unroll
        for (int j = 0; j < 16; ++j) {
            int n = t * 16 + j;
            float dx = __fsub_rn(xs[n], cx);
            float dy = __fsub_rn(ys[n], cy);
            float dz = __fsub_rn(zs[n], cz);
            float d = __fadd_rn(__fadd_rn(__fmul_rn(dx, dx), __fmul_rn(dy, dy)), __fmul_rn(dz, dz));
            float dd = fminf(dist[j], d);
            dist[j] = dd;
            if (dd > bestv) { bestv = dd; bestn = n; }   // j ascending -> keep first max
        }
#pragma unroll
        for (int off = 32; off >= 1; off >>= 1) {
            float ov = __shfl_down(bestv, off);
            int   on = __shfl_down(bestn, off);
            if (ov > bestv || (ov == bestv && on < bestn)) { bestv = ov; bestn = on; }
        }
        int w = t >> 6, l = t & 63;
        if (l == 0) { redv[w] = bestv; redi[w] = bestn; }
        __syncthreads();
        if (t == 0) {
            float bv = redv[0]; int bn = redi[0];
            for (int ww = 1; ww < 4; ++ww) {
                float ov = redv[ww]; int on = redi[ww];
                if (ov > bv || (ov == bv && on < bn)) { bv = ov; bn = on; }
            }
            bcast = bn;
        }
        __syncthreads();
        far = bcast;
    }
}

// ---------------- Ball query: one wave per (b,s), exact-match sq ----------------
__global__ __launch_bounds__(256) void ballquery_kernel(const float* __restrict__ xyz,
                                                        const float* __restrict__ nx,
                                                        int* __restrict__ gidx) {
    int wid = blockIdx.x * 4 + (threadIdx.x >> 6);   // b*SS + s
    int l = threadIdx.x & 63;
    int b = wid >> 10;
    const float* xb = xyz + b * 3 * NPTS;
    float qx = nx[wid * 3 + 0];
    float qy = nx[wid * 3 + 1];
    float qz = nx[wid * 3 + 2];
    float a = __fadd_rn(__fadd_rn(__fmul_rn(qx, qx), __fmul_rn(qy, qy)), __fmul_rn(qz, qz));
    int* g = gidx + wid * KS;
    int cnt = 0, first = -1;
    for (int base = 0; base < NPTS; base += 64) {
        int n = base + l;
        float x = xb[n], y = xb[NPTS + n], z = xb[2 * NPTS + n];
        float bn = __fadd_rn(__fadd_rn(__fmul_rn(x, x), __fmul_rn(y, y)), __fmul_rn(z, z));
        float dt = __fadd_rn(__fadd_rn(__fmul_rn(qx, x), __fmul_rn(qy, y)), __fmul_rn(qz, z));
        float sq = __fadd_rn(__fsub_rn(a, __fmul_rn(2.0f, dt)), bn);
        bool qual = (sq <= 0.04f);
        unsigned long long m = __ballot(qual);
        if (qual) {
            int pos = __popcll(m & ((1ull << l) - 1ull));
            int slot = cnt + pos;
            if (slot < KS) g[slot] = n;
        }
        if (first < 0 && m != 0ull) first = base + __ffsll((long long)m) - 1;
        cnt += __popcll(m);
        if (cnt >= KS) break;
    }
    if (cnt < KS) {
        int f = (first >= 0) ? first : 0;
        int slot = cnt + l;
        if (slot < KS) g[slot] = f;
    }
}

// ---------------- Gather + MLP(67->64->64->128, relu) + pos-enc -> P_b (K,S,C), one batch ----------------
__global__ __launch_bounds__(256) void group_mlp_kernel(
        const float* __restrict__ xyz, const float* __restrict__ pts,
        const float* __restrict__ nx, const int* __restrict__ gidx,
        const float* __restrict__ w0, const float* __restrict__ b0,
        const float* __restrict__ w1, const float* __restrict__ b1,
        const float* __restrict__ w2, const float* __restrict__ b2,
        const float* __restrict__ wpos, float* __restrict__ P, int b) {
    int s = blockIdx.x;
    int t = threadIdx.x;
    __shared__ float xin[32][68];
    __shared__ float gxs[32][4];
    __shared__ float h1[32][64];
    __shared__ float h2[32][64];
    __shared__ float wsm[8192];
    __shared__ float bb[128];
    __shared__ int idxs[32];
    int bs = b * SS + s;
    if (t < 32) idxs[t] = gidx[bs * KS + t];
    __syncthreads();
    float qx = nx[bs * 3 + 0], qy = nx[bs * 3 + 1], qz = nx[bs * 3 + 2];
    {
        int k = t >> 3, c0 = t & 7;
        int n = idxs[k];
        for (int c = c0; c < 67; c += 8) {
            float v;
            if (c < 3) {
                v = xyz[(b * 3 + c) * NPTS + n];
                gxs[k][c] = v;
                v = v - (c == 0 ? qx : (c == 1 ? qy : qz));
            } else {
                v = pts[(b * DIN + (c - 3)) * NPTS + n];
            }
            xin[k][c] = v;
        }
    }
    for (int u = t; u < 64 * 67; u += 256) wsm[u] = w0[u];
    if (t < 64) bb[t] = b0[t];
    __syncthreads();
    {
        int k = t >> 3, o0 = (t & 7) * 8;
        float acc[8] = {0,0,0,0,0,0,0,0};
        for (int c = 0; c < 67; ++c) {
            float xv = xin[k][c];
#pragma unroll
            for (int oo = 0; oo < 8; ++oo) acc[oo] += xv * wsm[(o0 + oo) * 67 + c];
        }
#pragma unroll
        for (int oo = 0; oo < 8; ++oo) h1[k][o0 + oo] = fmaxf(acc[oo] + bb[o0 + oo], 0.0f);
    }
    __syncthreads();
    for (int u = t; u < 64 * 64; u += 256) wsm[u] = w1[u];
    if (t < 64) bb[t] = b1[t];
    __syncthreads();
    {
        int k = t >> 3, o0 = (t & 7) * 8;
        float acc[8] = {0,0,0,0,0,0,0,0};
        for (int c = 0; c < 64; ++c) {
            float xv = h1[k][c];
#pragma unroll
            for (int oo = 0; oo < 8; ++oo) acc[oo] += xv * wsm[(o0 + oo) * 64 + c];
        }
#pragma unroll
        for (int oo = 0; oo < 8; ++oo) h2[k][o0 + oo] = fmaxf(acc[oo] + bb[o0 + oo], 0.0f);
    }
    __syncthreads();
    for (int u = t; u < 128 * 64; u += 256) wsm[u] = w2[u];
    if (t < 128) bb[t] = b2[t];
    __syncthreads();
    {
        int k = t >> 3, o0 = (t & 7) * 16;
        float acc[16];
#pragma unroll
        for (int oo = 0; oo < 16; ++oo) acc[oo] = 0.0f;
        for (int c = 0; c < 64; ++c) {
            float xv = h2[k][c];
#pragma unroll
            for (int oo = 0; oo < 16; ++oo) acc[oo] += xv * wsm[(o0 + oo) * 64 + c];
        }
        float g0 = gxs[k][0], g1 = gxs[k][1], g2 = gxs[k][2];
        int row = k * SS + s;                 // per-batch P: (K,S,C)
#pragma unroll
        for (int oo = 0; oo < 16; ++oo) {
            int o = o0 + oo;
            float v = fmaxf(acc[oo] + bb[o], 0.0f);
            v += g0 * wpos[o * 3 + 0] + g1 * wpos[o * 3 + 1] + g2 * wpos[o * 3 + 2];
            P[row * CC + o] = v;
        }
    }
}

// ---------------- QKV: (32768x128) @ (128x128) x3, one batch ----------------
__global__ __launch_bounds__(256) void qkv_kernel(const float* __restrict__ P,
                                                  const float* __restrict__ wq,
                                                  const float* __restrict__ wk,
                                                  const float* __restrict__ wv,
                                                  float* __restrict__ Qg,
                                                  float* __restrict__ Kg,
                                                  float* __restrict__ Vg) {
    __shared__ float pin[64 * 132];
    __shared__ float wsh[32 * 128];
    int t = threadIdx.x, ti = t & 15, tj = t >> 4;
    int r0 = blockIdx.x * 64;
    for (int u = t; u < 64 * 32; u += 256) {
        int r = u >> 5, c4 = (u & 31) * 4;
        const float4 v = *(const float4*)(P + (r0 + r) * CC + c4);
        pin[r * 132 + c4 + 0] = v.x; pin[r * 132 + c4 + 1] = v.y;
        pin[r * 132 + c4 + 2] = v.z; pin[r * 132 + c4 + 3] = v.w;
    }
    const float* wm[3] = {wq, wk, wv};
    float* om[3] = {Qg, Kg, Vg};
    for (int m = 0; m < 3; ++m) {
        float acc[4][8];
#pragma unroll
        for (int rr = 0; rr < 4; ++rr)
#pragma unroll
            for (int u = 0; u < 8; ++u) acc[rr][u] = 0.0f;
        const float* w = wm[m];
        for (int c0 = 0; c0 < 128; c0 += 32) {
            __syncthreads();
            for (int u = t; u < 32 * 32; u += 256) {
                int cc = u >> 5, o4 = (u & 31) * 4;
                *(float4*)&wsh[cc * 128 + o4] = *(const float4*)(w + (c0 + cc) * 128 + o4);
            }
            __syncthreads();
            for (int cc = 0; cc < 32; ++cc) {
                float pv[4];
#pragma unroll
                for (int rr = 0; rr < 4; ++rr) pv[rr] = pin[(tj * 4 + rr) * 132 + c0 + cc];
#pragma unroll
                for (int u = 0; u < 4; ++u) {
                    float2 wv2 = *(const float2*)&wsh[cc * 128 + ti * 2 + u * 32];
#pragma unroll
                    for (int rr = 0; rr < 4; ++rr) {
                        acc[rr][u * 2 + 0] += pv[rr] * wv2.x;
                        acc[rr][u * 2 + 1] += pv[rr] * wv2.y;
                    }
                }
            }
        }
        float* og = om[m];
#pragma unroll
        for (int rr = 0; rr < 4; ++rr) {
            int row = r0 + tj * 4 + rr;
#pragma unroll
            for (int u = 0; u < 4; ++u) {
                float2 o2 = make_float2(acc[rr][u * 2], acc[rr][u * 2 + 1]);
                *(float2*)(og + row * CC + ti * 2 + u * 32) = o2;
            }
        }
    }
}

// ---------------- Flash attention, one batch: 32x32 tiles, static LDS < 64KB ----------------
// blockIdx.x = head*32 + qtile. O written in place into Qg.
__global__ __launch_bounds__(256) void attn_kernel(float* __restrict__ Qg,
                                                   const float* __restrict__ Kg,
                                                   const float* __restrict__ Vg) {
    __shared__ float Qs[32 * 132];
    __shared__ float Ks[32 * 132];
    __shared__ float Vs[32 * 132];
    __shared__ float Ps[32 * 33];
    int t = threadIdx.x, ti = t & 15, tj = t >> 4;
    int head = blockIdx.x >> 5, qt = blockIdx.x & 31;
    int r0 = head * SS + qt * 32;
    int hr = head * SS;
    for (int u = t; u < 32 * 32; u += 256) {
        int r = u >> 5, c4 = (u & 31) * 4;
        const float4 v = *(const float4*)(Qg + (r0 + r) * CC + c4);
        Qs[r * 132 + c4 + 0] = v.x; Qs[r * 132 + c4 + 1] = v.y;
        Qs[r * 132 + c4 + 2] = v.z; Qs[r * 132 + c4 + 3] = v.w;
    }
    float m[2], l[2], oacc[2][8];
#pragma unroll
    for (int rr = 0; rr < 2; ++rr) {
        m[rr] = -1e30f; l[rr] = 0.0f;
#pragma unroll
        for (int u = 0; u < 8; ++u) oacc[rr][u] = 0.0f;
    }
    const float SCALE = 0.08838834764831845f;
    for (int kt = 0; kt < 32; ++kt) {
        __syncthreads();
        for (int u = t; u < 32 * 32; u += 256) {
            int r = u >> 5, c4 = (u & 31) * 4;
            const float4 kv = *(const float4*)(Kg + (hr + kt * 32 + r) * CC + c4);
            Ks[r * 132 + c4 + 0] = kv.x; Ks[r * 132 + c4 + 1] = kv.y;
            Ks[r * 132 + c4 + 2] = kv.z; Ks[r * 132 + c4 + 3] = kv.w;
            const float4 vv = *(const float4*)(Vg + (hr + kt * 32 + r) * CC + c4);
            Vs[r * 132 + c4 + 0] = vv.x; Vs[r * 132 + c4 + 1] = vv.y;
            Vs[r * 132 + c4 + 2] = vv.z; Vs[r * 132 + c4 + 3] = vv.w;
        }
        __syncthreads();
        float sc[2][2];
#pragma unroll
        for (int rr = 0; rr < 2; ++rr)
#pragma unroll
            for (int jj = 0; jj < 2; ++jj) sc[rr][jj] = 0.0f;
        for (int c2 = 0; c2 < 64; ++c2) {
            float2 qv[2], kv[2];
#pragma unroll
            for (int rr = 0; rr < 2; ++rr) qv[rr] = *(const float2*)&Qs[(tj * 2 + rr) * 132 + c2 * 2];
#pragma unroll
            for (int jj = 0; jj < 2; ++jj) kv[jj] = *(const float2*)&Ks[(ti * 2 + jj) * 132 + c2 * 2];
#pragma unroll
            for (int rr = 0; rr < 2; ++rr)
#pragma unroll
                for (int jj = 0; jj < 2; ++jj)
                    sc[rr][jj] += qv[rr].x * kv[jj].x + qv[rr].y * kv[jj].y;
        }
#pragma unroll
        for (int rr = 0; rr < 2; ++rr) {
            float z[2]; float mloc;
#pragma unroll
            for (int jj = 0; jj < 2; ++jj) z[jj] = sc[rr][jj] * SCALE;
            mloc = fmaxf(z[0], z[1]);
#pragma unroll
            for (int off = 1; off < 16; off <<= 1) mloc = fmaxf(mloc, __shfl_xor(mloc, off));
            float mnew = fmaxf(m[rr], mloc);
            float f = expf(m[rr] - mnew);
            float ssum = 0.0f;
#pragma unroll
            for (int jj = 0; jj < 2; ++jj) {
                float p = expf(z[jj] - mnew);
                Ps[(tj * 2 + rr) * 33 + ti * 2 + jj] = p;
                ssum += p;
            }
#pragma unroll
            for (int off = 1; off < 16; off <<= 1) ssum += __shfl_xor(ssum, off);
            l[rr] = l[rr] * f + ssum;
            m[rr] = mnew;
#pragma unroll
            for (int u = 0; u < 8; ++u) oacc[rr][u] *= f;
        }
        __syncthreads();
        for (int j = 0; j < 32; ++j) {
            float pv[2];
#pragma unroll
            for (int rr = 0; rr < 2; ++rr) pv[rr] = Ps[(tj * 2 + rr) * 33 + j];
#pragma unroll
            for (int u = 0; u < 4; ++u) {
                float2 vv = *(const float2*)&Vs[j * 132 + ti * 2 + u * 32];
#pragma unroll
                for (int rr = 0; rr < 2; ++rr) {
                    oacc[rr][u * 2 + 0] += pv[rr] * vv.x;
                    oacc[rr][u * 2 + 1] += pv[rr] * vv.y;
                }
            }
        }
    }
#pragma unroll
    for (int rr = 0; rr < 2; ++rr) {
        float inv = 1.0f / l[rr];
        int row = r0 + tj * 2 + rr;
#pragma unroll
        for (int u = 0; u < 4; ++u) {
            float2 o2 = make_float2(oacc[rr][u * 2] * inv, oacc[rr][u * 2 + 1] * inv);
            *(float2*)(Qg + row * CC + ti * 2 + u * 32) = o2;
        }
    }
}

// ---------------- P += O @ wo (in place on P), one batch ----------------
__global__ __launch_bounds__(256) void wo_kernel(const float* __restrict__ O,
                                                 const float* __restrict__ wo,
                                                 float* __restrict__ P) {
    __shared__ float pin[64 * 132];
    __shared__ float wsh[32 * 128];
    int t = threadIdx.x, ti = t & 15, tj = t >> 4;
    int r0 = blockIdx.x * 64;
    for (int u = t; u < 64 * 32; u += 256) {
        int r = u >> 5, c4 = (u & 31) * 4;
        const float4 v = *(const float4*)(O + (r0 + r) * CC + c4);
        pin[r * 132 + c4 + 0] = v.x; pin[r * 132 + c4 + 1] = v.y;
        pin[r * 132 + c4 + 2] = v.z; pin[r * 132 + c4 + 3] = v.w;
    }
    float acc[4][8];
#pragma unroll
    for (int rr = 0; rr < 4; ++rr)
#pragma unroll
        for (int u = 0; u < 8; ++u) acc[rr][u] = 0.0f;
    for (int c0 = 0; c0 < 128; c0 += 32) {
        __syncthreads();
        for (int u = t; u < 32 * 32; u += 256) {
            int cc = u >> 5, o4 = (u & 31) * 4;
            *(float4*)&wsh[cc * 128 + o4] = *(const float4*)(wo + (c0 + cc) * 128 + o4);
        }
        __syncthreads();
        for (int cc = 0; cc < 32; ++cc) {
            float pv[4];
#pragma unroll
            for (int rr = 0; rr < 4; ++rr) pv[rr] = pin[(tj * 4 + rr) * 132 + c0 + cc];
#pragma unroll
            for (int u = 0; u < 4; ++u) {
                float2 wv2 = *(const float2*)&wsh[cc * 128 + ti * 2 + u * 32];
#pragma unroll
                for (int rr = 0; rr < 4; ++rr) {
                    acc[rr][u * 2 + 0] += pv[rr] * wv2.x;
                    acc[rr][u * 2 + 1] += pv[rr] * wv2.y;
                }
            }
        }
    }
#pragma unroll
    for (int rr = 0; rr < 4; ++rr) {
        int row = r0 + tj * 4 + rr;
#pragma unroll
        for (int u = 0; u < 4; ++u) {
            float* dst = P + row * CC + ti * 2 + u * 32;
            float2 pold = *(const float2*)dst;
            float2 o2 = make_float2(pold.x + acc[rr][u * 2], pold.y + acc[rr][u * 2 + 1]);
            *(float2*)dst = o2;
        }
    }
}

// ---------------- maxpool over k -> out_b (C,S), one batch ----------------
__global__ __launch_bounds__(256) void maxpool_kernel(const float* __restrict__ P,
                                                      float* __restrict__ out_b) {
    int s = blockIdx.x * 2 + (threadIdx.x >> 7);
    int c = threadIdx.x & 127;
    const float* base = P + s * CC + c;
    float v = -1e30f;
#pragma unroll 4
    for (int k = 0; k < KS; ++k) v = fmaxf(v, base[k * SS * CC]);
    out_b[c * SS + s] = v;
}

extern "C" void kernel_launch(void* const* d_in, const int* in_sizes, int n_in,
                              void* d_out, int out_size, void* d_ws, size_t ws_size,
                              hipStream_t stream) {
    const float* xyz  = (const float*)d_in[0];
    const float* pts  = (const float*)d_in[1];
    const float* w0   = (const float*)d_in[2];
    const float* b0   = (const float*)d_in[3];
    const float* w1   = (const float*)d_in[4];
    const float* b1   = (const float*)d_in[5];
    const float* w2   = (const float*)d_in[6];
    const float* b2   = (const float*)d_in[7];
    const float* wq   = (const float*)d_in[8];
    const float* wk   = (const float*)d_in[9];
    const float* wv   = (const float*)d_in[10];
    const float* wo   = (const float*)d_in[11];
    const float* wpos = (const float*)d_in[12];
    float* out = (float*)d_out;
    char* ws = (char*)d_ws;
    float* nx  = (float*)(ws + WS_NX);
    int*  gidx = (int*)(ws + WS_GIDX);
    float* P   = (float*)(ws + WS_P);
    float* Qb  = (float*)(ws + WS_Q);
    float* Kb  = (float*)(ws + WS_K);
    float* Vb  = (float*)(ws + WS_V);

    fps_kernel<<<NB, 256, 0, stream>>>(xyz, out, nx);
    ballquery_kernel<<<(NB * SS) / 4, 256, 0, stream>>>(xyz, nx, gidx);
    for (int b = 0; b < NB; ++b) {
        group_mlp_kernel<<<SS, 256, 0, stream>>>(xyz, pts, nx, gidx,
                                                 w0, b0, w1, b1, w2, b2, wpos, P, b);
        qkv_kernel<<<(KS * SS) / 64, 256, 0, stream>>>(P, wq, wk, wv, Qb, Kb, Vb);
        attn_kernel<<<KS * (SS / 32), 256, 0, stream>>>(Qb, Kb, Vb);
        wo_kernel<<<(KS * SS) / 64, 256, 0, stream>>>(Qb, wo, P);
        maxpool_kernel<<<SS / 2, 256, 0, stream>>>(P, out + NB * 3 * SS + b * CC * SS);
    }
}

// Round 8
// 8838.301 us; speedup vs baseline: 1.1712x; 1.1712x over previous
//
#include <hip/hip_runtime.h>
#include <hip/hip_bf16.h>
#include <math.h>

#define NB 4
#define NPTS 4096
#define SS 1024
#define KS 32
#define DIN 64
#define CC 128

typedef __attribute__((ext_vector_type(8))) short bf16x8;
typedef __attribute__((ext_vector_type(4))) float f32x4;

// ws layout (bytes)
#define WS_NX   0u                       // float[4*1024*3]
#define WS_GIDX 49152u                   // int[4*1024*32]
#define WS_P    (1u<<20)                 // float[32768*128] one batch (16MB)
#define WS_QB   (WS_P  + 16777216u)      // bf16 [32768*128] (8MB)
#define WS_KB   (WS_QB + 8388608u)
#define WS_VB   (WS_KB + 8388608u)
#define WS_OB   (WS_VB + 8388608u)       // float[32768*128] (16MB) -> end 57MB

// ---------------- FPS: 1 block per batch, exact-match arithmetic ----------------
__global__ __launch_bounds__(256) void fps_kernel(const float* __restrict__ xyz,
                                                  float* __restrict__ out_newxyz,
                                                  float* __restrict__ ws_nx) {
    int b = blockIdx.x;
    const float* xb = xyz + b * 3 * NPTS;
    __shared__ float xs[NPTS], ys[NPTS], zs[NPTS];
    __shared__ float redv[4];
    __shared__ int   redi[4];
    __shared__ int   bcast;
    int t = threadIdx.x;
    for (int n = t; n < NPTS; n += 256) {
        xs[n] = xb[n]; ys[n] = xb[NPTS + n]; zs[n] = xb[2 * NPTS + n];
    }
    __syncthreads();
    float dist[16];
#pragma unroll
    for (int j = 0; j < 16; ++j) dist[j] = 1e10f;
    int far = 0;
    for (int i = 0; i < SS; ++i) {
        float cx = xs[far], cy = ys[far], cz = zs[far];
        if (t == 0) {
            out_newxyz[b * 3 * SS + 0 * SS + i] = cx;
            out_newxyz[b * 3 * SS + 1 * SS + i] = cy;
            out_newxyz[b * 3 * SS + 2 * SS + i] = cz;
            ws_nx[(b * SS + i) * 3 + 0] = cx;
            ws_nx[(b * SS + i) * 3 + 1] = cy;
            ws_nx[(b * SS + i) * 3 + 2] = cz;
        }
        float bestv = -1.0f; int bestn = 0;
#pragma unroll
        for (int j = 0; j < 16; ++j) {
            int n = j * 256 + t;      // lane-consecutive: conflict-free LDS
            float dx = __fsub_rn(xs[n], cx);
            float dy = __fsub_rn(ys[n], cy);
            float dz = __fsub_rn(zs[n], cz);
            float d = __fadd_rn(__fadd_rn(__fmul_rn(dx, dx), __fmul_rn(dy, dy)), __fmul_rn(dz, dz));
            float dd = fminf(dist[j], d);
            dist[j] = dd;
            if (dd > bestv) { bestv = dd; bestn = n; }   // n ascending in j -> first max kept
        }
#pragma unroll
        for (int off = 32; off >= 1; off >>= 1) {
            float ov = __shfl_down(bestv, off);
            int   on = __shfl_down(bestn, off);
            if (ov > bestv || (ov == bestv && on < bestn)) { bestv = ov; bestn = on; }
        }
        int w = t >> 6, l = t & 63;
        if (l == 0) { redv[w] = bestv; redi[w] = bestn; }
        __syncthreads();
        if (t == 0) {
            float bv = redv[0]; int bn = redi[0];
            for (int ww = 1; ww < 4; ++ww) {
                float ov = redv[ww]; int on = redi[ww];
                if (ov > bv || (ov == bv && on < bn)) { bv = ov; bn = on; }
            }
            bcast = bn;
        }
        __syncthreads();
        far = bcast;
    }
}

// ---------------- Ball query: one wave per (b,s), exact-match sq ----------------
__global__ __launch_bounds__(256) void ballquery_kernel(const float* __restrict__ xyz,
                                                        const float* __restrict__ nx,
                                                        int* __restrict__ gidx) {
    int wid = blockIdx.x * 4 + (threadIdx.x >> 6);   // b*SS + s
    int l = threadIdx.x & 63;
    int b = wid >> 10;
    const float* xb = xyz + b * 3 * NPTS;
    float qx = nx[wid * 3 + 0];
    float qy = nx[wid * 3 + 1];
    float qz = nx[wid * 3 + 2];
    float a = __fadd_rn(__fadd_rn(__fmul_rn(qx, qx), __fmul_rn(qy, qy)), __fmul_rn(qz, qz));
    int* g = gidx + wid * KS;
    int cnt = 0, first = -1;
    for (int base = 0; base < NPTS; base += 64) {
        int n = base + l;
        float x = xb[n], y = xb[NPTS + n], z = xb[2 * NPTS + n];
        float bn = __fadd_rn(__fadd_rn(__fmul_rn(x, x), __fmul_rn(y, y)), __fmul_rn(z, z));
        float dt = __fadd_rn(__fadd_rn(__fmul_rn(qx, x), __fmul_rn(qy, y)), __fmul_rn(qz, z));
        float sq = __fadd_rn(__fsub_rn(a, __fmul_rn(2.0f, dt)), bn);
        bool qual = (sq <= 0.04f);
        unsigned long long m = __ballot(qual);
        if (qual) {
            int pos = __popcll(m & ((1ull << l) - 1ull));
            int slot = cnt + pos;
            if (slot < KS) g[slot] = n;
        }
        if (first < 0 && m != 0ull) first = base + __ffsll((long long)m) - 1;
        cnt += __popcll(m);
        if (cnt >= KS) break;
    }
    if (cnt < KS) {
        int f = (first >= 0) ? first : 0;
        int slot = cnt + l;
        if (slot < KS) g[slot] = f;
    }
}

// ---------------- Gather + MLP(67->64->64->128, relu) + pos-enc -> P_b (K,S,C) ----------------
__global__ __launch_bounds__(256) void group_mlp_kernel(
        const float* __restrict__ xyz, const float* __restrict__ pts,
        const float* __restrict__ nx, const int* __restrict__ gidx,
        const float* __restrict__ w0, const float* __restrict__ b0,
        const float* __restrict__ w1, const float* __restrict__ b1,
        const float* __restrict__ w2, const float* __restrict__ b2,
        const float* __restrict__ wpos, float* __restrict__ P, int b) {
    int s = blockIdx.x;
    int t = threadIdx.x;
    __shared__ float xin[32][68];
    __shared__ float gxs[32][4];
    __shared__ float h1[32][64];
    __shared__ float h2[32][64];
    __shared__ float wsm[8192];
    __shared__ float bb[128];
    __shared__ int idxs[32];
    int bs = b * SS + s;
    if (t < 32) idxs[t] = gidx[bs * KS + t];
    __syncthreads();
    float qx = nx[bs * 3 + 0], qy = nx[bs * 3 + 1], qz = nx[bs * 3 + 2];
    {
        int k = t >> 3, c0 = t & 7;
        int n = idxs[k];
        for (int c = c0; c < 67; c += 8) {
            float v;
            if (c < 3) {
                v = xyz[(b * 3 + c) * NPTS + n];
                gxs[k][c] = v;
                v = v - (c == 0 ? qx : (c == 1 ? qy : qz));
            } else {
                v = pts[(b * DIN + (c - 3)) * NPTS + n];
            }
            xin[k][c] = v;
        }
    }
    for (int u = t; u < 64 * 67; u += 256) wsm[u] = w0[u];
    if (t < 64) bb[t] = b0[t];
    __syncthreads();
    {
        int k = t >> 3, o0 = (t & 7) * 8;
        float acc[8] = {0,0,0,0,0,0,0,0};
        for (int c = 0; c < 67; ++c) {
            float xv = xin[k][c];
#pragma unroll
            for (int oo = 0; oo < 8; ++oo) acc[oo] += xv * wsm[(o0 + oo) * 67 + c];
        }
#pragma unroll
        for (int oo = 0; oo < 8; ++oo) h1[k][o0 + oo] = fmaxf(acc[oo] + bb[o0 + oo], 0.0f);
    }
    __syncthreads();
    for (int u = t; u < 64 * 64; u += 256) wsm[u] = w1[u];
    if (t < 64) bb[t] = b1[t];
    __syncthreads();
    {
        int k = t >> 3, o0 = (t & 7) * 8;
        float acc[8] = {0,0,0,0,0,0,0,0};
        for (int c = 0; c < 64; ++c) {
            float xv = h1[k][c];
#pragma unroll
            for (int oo = 0; oo < 8; ++oo) acc[oo] += xv * wsm[(o0 + oo) * 64 + c];
        }
#pragma unroll
        for (int oo = 0; oo < 8; ++oo) h2[k][o0 + oo] = fmaxf(acc[oo] + bb[o0 + oo], 0.0f);
    }
    __syncthreads();
    for (int u = t; u < 128 * 64; u += 256) wsm[u] = w2[u];
    if (t < 128) bb[t] = b2[t];
    __syncthreads();
    {
        int k = t >> 3, o0 = (t & 7) * 16;
        float acc[16];
#pragma unroll
        for (int oo = 0; oo < 16; ++oo) acc[oo] = 0.0f;
        for (int c = 0; c < 64; ++c) {
            float xv = h2[k][c];
#pragma unroll
            for (int oo = 0; oo < 16; ++oo) acc[oo] += xv * wsm[(o0 + oo) * 64 + c];
        }
        float g0 = gxs[k][0], g1 = gxs[k][1], g2 = gxs[k][2];
        int row = k * SS + s;
#pragma unroll
        for (int oo = 0; oo < 16; ++oo) {
            int o = o0 + oo;
            float v = fmaxf(acc[oo] + bb[o], 0.0f);
            v += g0 * wpos[o * 3 + 0] + g1 * wpos[o * 3 + 1] + g2 * wpos[o * 3 + 2];
            P[row * CC + o] = v;
        }
    }
}

// ---------------- QKV: (32768x128)@(128x128) x3 -> bf16 (Q pre-scaled) ----------------
__global__ __launch_bounds__(256) void qkv_kernel(const float* __restrict__ P,
                                                  const float* __restrict__ wq,
                                                  const float* __restrict__ wk,
                                                  const float* __restrict__ wv,
                                                  ushort* __restrict__ Qg,
                                                  ushort* __restrict__ Kg,
                                                  ushort* __restrict__ Vg) {
    __shared__ float pin[64 * 132];
    __shared__ float wsh[32 * 128];
    int t = threadIdx.x, ti = t & 15, tj = t >> 4;
    int r0 = blockIdx.x * 64;
    for (int u = t; u < 64 * 32; u += 256) {
        int r = u >> 5, c4 = (u & 31) * 4;
        const float4 v = *(const float4*)(P + (r0 + r) * CC + c4);
        pin[r * 132 + c4 + 0] = v.x; pin[r * 132 + c4 + 1] = v.y;
        pin[r * 132 + c4 + 2] = v.z; pin[r * 132 + c4 + 3] = v.w;
    }
    const float* wm[3] = {wq, wk, wv};
    ushort* om[3] = {Qg, Kg, Vg};
    for (int m = 0; m < 3; ++m) {
        float acc[4][8];
#pragma unroll
        for (int rr = 0; rr < 4; ++rr)
#pragma unroll
            for (int u = 0; u < 8; ++u) acc[rr][u] = 0.0f;
        const float* w = wm[m];
        for (int c0 = 0; c0 < 128; c0 += 32) {
            __syncthreads();
            for (int u = t; u < 32 * 32; u += 256) {
                int cc = u >> 5, o4 = (u & 31) * 4;
                *(float4*)&wsh[cc * 128 + o4] = *(const float4*)(w + (c0 + cc) * 128 + o4);
            }
            __syncthreads();
            for (int cc = 0; cc < 32; ++cc) {
                float pv[4];
#pragma unroll
                for (int rr = 0; rr < 4; ++rr) pv[rr] = pin[(tj * 4 + rr) * 132 + c0 + cc];
#pragma unroll
                for (int u = 0; u < 4; ++u) {
                    float2 wv2 = *(const float2*)&wsh[cc * 128 + ti * 2 + u * 32];
#pragma unroll
                    for (int rr = 0; rr < 4; ++rr) {
                        acc[rr][u * 2 + 0] += pv[rr] * wv2.x;
                        acc[rr][u * 2 + 1] += pv[rr] * wv2.y;
                    }
                }
            }
        }
        ushort* og = om[m];
        float s = (m == 0) ? 0.08838834764831845f : 1.0f;   // fold 1/sqrt(C) into Q
#pragma unroll
        for (int rr = 0; rr < 4; ++rr) {
            int row = r0 + tj * 4 + rr;
#pragma unroll
            for (int u = 0; u < 4; ++u) {
                __hip_bfloat16 h0 = __float2bfloat16(acc[rr][u * 2 + 0] * s);
                __hip_bfloat16 h1 = __float2bfloat16(acc[rr][u * 2 + 1] * s);
                ushort2 o2 = make_ushort2(*(ushort*)&h0, *(ushort*)&h1);
                *(ushort2*)(og + row * CC + ti * 2 + u * 32) = o2;
            }
        }
    }
}

// ---------------- Flash attention, bf16 MFMA 16x16x32, one batch ----------------
// block = 256 thr = 4 warps; per block: 64 q-rows (warp -> 16), KT=32, 32 k-iters.
// A 128-bf16 row = 256B = SIXTEEN int4 chunks (r7 bugfix: was 8 -> upper half stale).
__global__ __launch_bounds__(256) void attn_kernel(const ushort* __restrict__ Qg,
                                                   const ushort* __restrict__ Kg,
                                                   const ushort* __restrict__ Vg,
                                                   float* __restrict__ Og) {
    __shared__ ushort Qs[64 * 136];
    __shared__ ushort Ks[32 * 136];
    __shared__ ushort Vt[128 * 40];    // V transposed: Vt[d][k]
    __shared__ ushort Ps[4 * 16 * 40]; // per-warp P tile [q 16][k 32]
    int t = threadIdx.x;
    int w = t >> 6, l = t & 63, g = l >> 4, c = l & 15;
    int head = blockIdx.x >> 4, qt = blockIdx.x & 15;
    int r0 = head * SS + qt * 64;
    int hr = head * SS;
    // stage Q (bf16, pre-scaled): 64 rows x 16 16B-chunks
    for (int idx = t; idx < 64 * 16; idx += 256) {
        int r = idx >> 4, ch = idx & 15;
        *(int4*)&Qs[r * 136 + ch * 8] = *(const int4*)&Qg[(r0 + r) * CC + ch * 8];
    }
    f32x4 oacc[8];
    float mrun[4], lrun[4];
#pragma unroll
    for (int d = 0; d < 8; ++d) oacc[d] = (f32x4){0.f, 0.f, 0.f, 0.f};
#pragma unroll
    for (int r = 0; r < 4; ++r) { mrun[r] = -1e30f; lrun[r] = 0.0f; }
    ushort* psw = &Ps[w * 16 * 40];

    for (int kt = 0; kt < 32; ++kt) {
        __syncthreads();
        // stage K: 32 rows x 16 chunks = 512
        for (int idx = t; idx < 32 * 16; idx += 256) {
            int r = idx >> 4, ch = idx & 15;
            *(int4*)&Ks[r * 136 + ch * 8] = *(const int4*)&Kg[(hr + kt * 32 + r) * CC + ch * 8];
        }
#pragma unroll
        for (int h = 0; h < 2; ++h) {  // stage V transposed: conflict-free LDS writes
            int r = t & 31, cg = (t >> 5) + h * 8;
            int4 vv = *(const int4*)&Vg[(hr + kt * 32 + r) * CC + cg * 8];
            const ushort* us = (const ushort*)&vv;
#pragma unroll
            for (int e = 0; e < 8; ++e) Vt[(cg * 8 + e) * 40 + r] = us[e];
        }
        __syncthreads();
        // QK^T: A = Q rows, B = K rows (B-frag of K^T), chained over 4 c-chunks
        f32x4 sc0 = (f32x4){0.f, 0.f, 0.f, 0.f};
        f32x4 sc1 = (f32x4){0.f, 0.f, 0.f, 0.f};
#pragma unroll
        for (int ck = 0; ck < 4; ++ck) {
            bf16x8 a  = *(const bf16x8*)&Qs[(w * 16 + c) * 136 + ck * 32 + g * 8];
            bf16x8 b0 = *(const bf16x8*)&Ks[c * 136 + ck * 32 + g * 8];
            bf16x8 b1 = *(const bf16x8*)&Ks[(16 + c) * 136 + ck * 32 + g * 8];
            sc0 = __builtin_amdgcn_mfma_f32_16x16x32_bf16(a, b0, sc0, 0, 0, 0);
            sc1 = __builtin_amdgcn_mfma_f32_16x16x32_bf16(a, b1, sc1, 0, 0, 0);
        }
        // online softmax: lane holds rows m=4g+r (regs), col c (+16 for sc1)
#pragma unroll
        for (int r = 0; r < 4; ++r) {
            float mx = fmaxf(sc0[r], sc1[r]);
#pragma unroll
            for (int off = 1; off < 16; off <<= 1) mx = fmaxf(mx, __shfl_xor(mx, off));
            float mn = fmaxf(mrun[r], mx);
            float f = __expf(mrun[r] - mn);
            mrun[r] = mn;
            float p0 = __expf(sc0[r] - mn);
            float p1 = __expf(sc1[r] - mn);
            __hip_bfloat16 hb0 = __float2bfloat16(p0);
            __hip_bfloat16 hb1 = __float2bfloat16(p1);
            psw[(4 * g + r) * 40 + c]      = *(ushort*)&hb0;
            psw[(4 * g + r) * 40 + 16 + c] = *(ushort*)&hb1;
            float ps = p0 + p1;
#pragma unroll
            for (int off = 1; off < 16; off <<= 1) ps += __shfl_xor(ps, off);
            lrun[r] = lrun[r] * f + ps;
#pragma unroll
            for (int d = 0; d < 8; ++d) oacc[d][r] *= f;
        }
        // PV: A = P rows (from Ps), B = Vt rows; one K=32 mfma per d-tile
        bf16x8 pa = *(const bf16x8*)&psw[c * 40 + g * 8];
#pragma unroll
        for (int d = 0; d < 8; ++d) {
            bf16x8 bv = *(const bf16x8*)&Vt[(d * 16 + c) * 40 + g * 8];
            oacc[d] = __builtin_amdgcn_mfma_f32_16x16x32_bf16(pa, bv, oacc[d], 0, 0, 0);
        }
    }
    // epilogue: O / l
#pragma unroll
    for (int r = 0; r < 4; ++r) {
        float inv = 1.0f / lrun[r];
        int row = r0 + w * 16 + 4 * g + r;
#pragma unroll
        for (int d = 0; d < 8; ++d)
            Og[row * CC + d * 16 + c] = oacc[d][r] * inv;
    }
}

// ---------------- P += O @ wo (in place on P), one batch ----------------
__global__ __launch_bounds__(256) void wo_kernel(const float* __restrict__ O,
                                                 const float* __restrict__ wo,
                                                 float* __restrict__ P) {
    __shared__ float pin[64 * 132];
    __shared__ float wsh[32 * 128];
    int t = threadIdx.x, ti = t & 15, tj = t >> 4;
    int r0 = blockIdx.x * 64;
    for (int u = t; u < 64 * 32; u += 256) {
        int r = u >> 5, c4 = (u & 31) * 4;
        const float4 v = *(const float4*)(O + (r0 + r) * CC + c4);
        pin[r * 132 + c4 + 0] = v.x; pin[r * 132 + c4 + 1] = v.y;
        pin[r * 132 + c4 + 2] = v.z; pin[r * 132 + c4 + 3] = v.w;
    }
    float acc[4][8];
#pragma unroll
    for (int rr = 0; rr < 4; ++rr)
#pragma unroll
        for (int u = 0; u < 8; ++u) acc[rr][u] = 0.0f;
    for (int c0 = 0; c0 < 128; c0 += 32) {
        __syncthreads();
        for (int u = t; u < 32 * 32; u += 256) {
            int cc = u >> 5, o4 = (u & 31) * 4;
            *(float4*)&wsh[cc * 128 + o4] = *(const float4*)(wo + (c0 + cc) * 128 + o4);
        }
        __syncthreads();
        for (int cc = 0; cc < 32; ++cc) {
            float pv[4];
#pragma unroll
            for (int rr = 0; rr < 4; ++rr) pv[rr] = pin[(tj * 4 + rr) * 132 + c0 + cc];
#pragma unroll
            for (int u = 0; u < 4; ++u) {
                float2 wv2 = *(const float2*)&wsh[cc * 128 + ti * 2 + u * 32];
#pragma unroll
                for (int rr = 0; rr < 4; ++rr) {
                    acc[rr][u * 2 + 0] += pv[rr] * wv2.x;
                    acc[rr][u * 2 + 1] += pv[rr] * wv2.y;
                }
            }
        }
    }
#pragma unroll
    for (int rr = 0; rr < 4; ++rr) {
        int row = r0 + tj * 4 + rr;
#pragma unroll
        for (int u = 0; u < 4; ++u) {
            float* dst = P + row * CC + ti * 2 + u * 32;
            float2 pold = *(const float2*)dst;
            float2 o2 = make_float2(pold.x + acc[rr][u * 2], pold.y + acc[rr][u * 2 + 1]);
            *(float2*)dst = o2;
        }
    }
}

// ---------------- maxpool over k -> out_b (C,S), one batch ----------------
__global__ __launch_bounds__(256) void maxpool_kernel(const float* __restrict__ P,
                                                      float* __restrict__ out_b) {
    int s = blockIdx.x * 2 + (threadIdx.x >> 7);
    int c = threadIdx.x & 127;
    const float* base = P + s * CC + c;
    float v = -1e30f;
#pragma unroll 4
    for (int k = 0; k < KS; ++k) v = fmaxf(v, base[k * SS * CC]);
    out_b[c * SS + s] = v;
}

extern "C" void kernel_launch(void* const* d_in, const int* in_sizes, int n_in,
                              void* d_out, int out_size, void* d_ws, size_t ws_size,
                              hipStream_t stream) {
    const float* xyz  = (const float*)d_in[0];
    const float* pts  = (const float*)d_in[1];
    const float* w0   = (const float*)d_in[2];
    const float* b0   = (const float*)d_in[3];
    const float* w1   = (const float*)d_in[4];
    const float* b1   = (const float*)d_in[5];
    const float* w2   = (const float*)d_in[6];
    const float* b2   = (const float*)d_in[7];
    const float* wq   = (const float*)d_in[8];
    const float* wk   = (const float*)d_in[9];
    const float* wv   = (const float*)d_in[10];
    const float* wo   = (const float*)d_in[11];
    const float* wpos = (const float*)d_in[12];
    float* out = (float*)d_out;
    char* ws = (char*)d_ws;
    float*  nx   = (float*)(ws + WS_NX);
    int*    gidx = (int*)(ws + WS_GIDX);
    float*  P    = (float*)(ws + WS_P);
    ushort* Qb   = (ushort*)(ws + WS_QB);
    ushort* Kb   = (ushort*)(ws + WS_KB);
    ushort* Vb   = (ushort*)(ws + WS_VB);
    float*  Ob   = (float*)(ws + WS_OB);

    fps_kernel<<<NB, 256, 0, stream>>>(xyz, out, nx);
    ballquery_kernel<<<(NB * SS) / 4, 256, 0, stream>>>(xyz, nx, gidx);
    for (int b = 0; b < NB; ++b) {
        group_mlp_kernel<<<SS, 256, 0, stream>>>(xyz, pts, nx, gidx,
                                                 w0, b0, w1, b1, w2, b2, wpos, P, b);
        qkv_kernel<<<(KS * SS) / 64, 256, 0, stream>>>(P, wq, wk, wv, Qb, Kb, Vb);
        attn_kernel<<<KS * (SS / 64), 256, 0, stream>>>(Qb, Kb, Vb, Ob);
        wo_kernel<<<(KS * SS) / 64, 256, 0, stream>>>(Ob, wo, P);
        maxpool_kernel<<<SS / 2, 256, 0, stream>>>(P, out + NB * 3 * SS + b * CC * SS);
    }
}

// Round 11
// 2632.763 us; speedup vs baseline: 3.9319x; 3.3570x over previous
//
#include <hip/hip_runtime.h>
#include <hip/hip_bf16.h>
#include <math.h>

#define NB 4
#define NPTS 4096
#define SS 1024
#define KS 32
#define DIN 64
#define CC 128

typedef __attribute__((ext_vector_type(8))) short bf16x8;
typedef __attribute__((ext_vector_type(4))) float f32x4;

#define SCALEQ 0.08838834764831845f

// ws layout (bytes)
#define WS_NX   0u                       // float[4*1024*3]
#define WS_GIDX 49152u                   // int[4*1024*32]
#define WS_P    (1u<<20)                 // float[32768*128] one batch (16MB)
#define WS_QB   (WS_P  + 16777216u)      // bf16 [32768*128] (8MB)
#define WS_KB   (WS_QB + 8388608u)
#define WS_VB   (WS_KB + 8388608u)
#define WS_OB   (WS_VB + 8388608u)       // bf16 [32768*128] (8MB)
#define WS_WT   (WS_OB + 8388608u)       // bf16 4x[128*128] transposed weights (128KB)

static __device__ __forceinline__ ushort f2bf(float x) {
    __hip_bfloat16 h = __float2bfloat16(x);
    return *(ushort*)&h;
}

// ---------------- prep: Wt[n][k] = bf16(w[k][n]) for wq,wk,wv,wo ----------------
__global__ __launch_bounds__(256) void prep_weights_kernel(const float* __restrict__ wq,
                                                           const float* __restrict__ wk,
                                                           const float* __restrict__ wv,
                                                           const float* __restrict__ wo,
                                                           ushort* __restrict__ dst) {
    const float* src = (blockIdx.x == 0) ? wq : (blockIdx.x == 1) ? wk
                      : (blockIdx.x == 2) ? wv : wo;
    ushort* d = dst + blockIdx.x * CC * CC;
    for (int idx = threadIdx.x; idx < CC * CC; idx += 256) {
        int k = idx >> 7, n = idx & 127;          // coalesced read along n
        d[n * CC + k] = f2bf(src[k * CC + n]);    // transposed write
    }
}

// ---------------- FPS: 1 block/batch, 1024 thr, exact-match arithmetic ----------------
__global__ __launch_bounds__(1024) void fps_kernel(const float* __restrict__ xyz,
                                                   float* __restrict__ out_newxyz,
                                                   float* __restrict__ ws_nx) {
    int b = blockIdx.x;
    const float* xb = xyz + b * 3 * NPTS;
    __shared__ float xs[NPTS], ys[NPTS], zs[NPTS];
    __shared__ float redv[16];
    __shared__ int   redi[16];
    __shared__ int   bcast;
    int t = threadIdx.x;
    for (int n = t; n < NPTS; n += 1024) {
        xs[n] = xb[n]; ys[n] = xb[NPTS + n]; zs[n] = xb[2 * NPTS + n];
    }
    __syncthreads();
    float dist[4];
#pragma unroll
    for (int j = 0; j < 4; ++j) dist[j] = 1e10f;
    int far = 0;
    int w = t >> 6, l = t & 63;
    for (int i = 0; i < SS; ++i) {
        float cx = xs[far], cy = ys[far], cz = zs[far];
        if (t == 0) {
            out_newxyz[b * 3 * SS + 0 * SS + i] = cx;
            out_newxyz[b * 3 * SS + 1 * SS + i] = cy;
            out_newxyz[b * 3 * SS + 2 * SS + i] = cz;
            ws_nx[(b * SS + i) * 3 + 0] = cx;
            ws_nx[(b * SS + i) * 3 + 1] = cy;
            ws_nx[(b * SS + i) * 3 + 2] = cz;
        }
        float bestv = -1.0f; int bestn = 0;
#pragma unroll
        for (int j = 0; j < 4; ++j) {
            int n = j * 1024 + t;     // lane-consecutive, conflict-free
            float dx = __fsub_rn(xs[n], cx);
            float dy = __fsub_rn(ys[n], cy);
            float dz = __fsub_rn(zs[n], cz);
            float d = __fadd_rn(__fadd_rn(__fmul_rn(dx, dx), __fmul_rn(dy, dy)), __fmul_rn(dz, dz));
            float dd = fminf(dist[j], d);
            dist[j] = dd;
            if (dd > bestv) { bestv = dd; bestn = n; }   // n ascending in j -> first max kept
        }
#pragma unroll
        for (int off = 32; off >= 1; off >>= 1) {
            float ov = __shfl_down(bestv, off);
            int   on = __shfl_down(bestn, off);
            if (ov > bestv || (ov == bestv && on < bestn)) { bestv = ov; bestn = on; }
        }
        if (l == 0) { redv[w] = bestv; redi[w] = bestn; }
        __syncthreads();
        if (t < 64) {
            float bv = (t < 16) ? redv[t] : -1.0f;
            int   bn = (t < 16) ? redi[t] : 0x7fffffff;
#pragma unroll
            for (int off = 8; off >= 1; off >>= 1) {
                float ov = __shfl_down(bv, off);
                int   on = __shfl_down(bn, off);
                if (ov > bv || (ov == bv && on < bn)) { bv = ov; bn = on; }
            }
            if (t == 0) bcast = bn;
        }
        __syncthreads();
        far = bcast;
    }
}

// ---------------- Ball query: one wave per (b,s), exact-match sq ----------------
__global__ __launch_bounds__(256) void ballquery_kernel(const float* __restrict__ xyz,
                                                        const float* __restrict__ nx,
                                                        int* __restrict__ gidx) {
    int wid = blockIdx.x * 4 + (threadIdx.x >> 6);   // b*SS + s
    int l = threadIdx.x & 63;
    int b = wid >> 10;
    const float* xb = xyz + b * 3 * NPTS;
    float qx = nx[wid * 3 + 0];
    float qy = nx[wid * 3 + 1];
    float qz = nx[wid * 3 + 2];
    float a = __fadd_rn(__fadd_rn(__fmul_rn(qx, qx), __fmul_rn(qy, qy)), __fmul_rn(qz, qz));
    int* g = gidx + wid * KS;
    int cnt = 0, first = -1;
    for (int base = 0; base < NPTS; base += 64) {
        int n = base + l;
        float x = xb[n], y = xb[NPTS + n], z = xb[2 * NPTS + n];
        float bn = __fadd_rn(__fadd_rn(__fmul_rn(x, x), __fmul_rn(y, y)), __fmul_rn(z, z));
        float dt = __fadd_rn(__fadd_rn(__fmul_rn(qx, x), __fmul_rn(qy, y)), __fmul_rn(qz, z));
        float sq = __fadd_rn(__fsub_rn(a, __fmul_rn(2.0f, dt)), bn);
        bool qual = (sq <= 0.04f);
        unsigned long long m = __ballot(qual);
        if (qual) {
            int pos = __popcll(m & ((1ull << l) - 1ull));
            int slot = cnt + pos;
            if (slot < KS) g[slot] = n;
        }
        if (first < 0 && m != 0ull) first = base + __ffsll((long long)m) - 1;
        cnt += __popcll(m);
        if (cnt >= KS) break;
    }
    if (cnt < KS) {
        int f = (first >= 0) ? first : 0;
        int slot = cnt + l;
        if (slot < KS) g[slot] = f;
    }
}

// ---------------- Gather + MLP(67->64->64->128, relu) + pos-enc -> P_b (K,S,C) ----------------
__global__ __launch_bounds__(256) void group_mlp_kernel(
        const float* __restrict__ xyz, const float* __restrict__ pts,
        const float* __restrict__ nx, const int* __restrict__ gidx,
        const float* __restrict__ w0, const float* __restrict__ b0,
        const float* __restrict__ w1, const float* __restrict__ b1,
        const float* __restrict__ w2, const float* __restrict__ b2,
        const float* __restrict__ wpos, float* __restrict__ P, int b) {
    int s = blockIdx.x;
    int t = threadIdx.x;
    __shared__ float xin[32][68];
    __shared__ float gxs[32][4];
    __shared__ float h1[32][64];
    __shared__ float h2[32][64];
    __shared__ float wsm[8192];
    __shared__ float bb[128];
    __shared__ int idxs[32];
    int bs = b * SS + s;
    if (t < 32) idxs[t] = gidx[bs * KS + t];
    __syncthreads();
    float qx = nx[bs * 3 + 0], qy = nx[bs * 3 + 1], qz = nx[bs * 3 + 2];
    {
        int k = t >> 3, c0 = t & 7;
        int n = idxs[k];
        for (int c = c0; c < 67; c += 8) {
            float v;
            if (c < 3) {
                v = xyz[(b * 3 + c) * NPTS + n];
                gxs[k][c] = v;
                v = v - (c == 0 ? qx : (c == 1 ? qy : qz));
            } else {
                v = pts[(b * DIN + (c - 3)) * NPTS + n];
            }
            xin[k][c] = v;
        }
    }
    for (int u = t; u < 64 * 67; u += 256) wsm[u] = w0[u];
    if (t < 64) bb[t] = b0[t];
    __syncthreads();
    {
        int k = t >> 3, o0 = (t & 7) * 8;
        float acc[8] = {0,0,0,0,0,0,0,0};
        for (int c = 0; c < 67; ++c) {
            float xv = xin[k][c];
#pragma unroll
            for (int oo = 0; oo < 8; ++oo) acc[oo] += xv * wsm[(o0 + oo) * 67 + c];
        }
#pragma unroll
        for (int oo = 0; oo < 8; ++oo) h1[k][o0 + oo] = fmaxf(acc[oo] + bb[o0 + oo], 0.0f);
    }
    __syncthreads();
    for (int u = t; u < 64 * 64; u += 256) wsm[u] = w1[u];
    if (t < 64) bb[t] = b1[t];
    __syncthreads();
    {
        int k = t >> 3, o0 = (t & 7) * 8;
        float acc[8] = {0,0,0,0,0,0,0,0};
        for (int c = 0; c < 64; ++c) {
            float xv = h1[k][c];
#pragma unroll
            for (int oo = 0; oo < 8; ++oo) acc[oo] += xv * wsm[(o0 + oo) * 64 + c];
        }
#pragma unroll
        for (int oo = 0; oo < 8; ++oo) h2[k][o0 + oo] = fmaxf(acc[oo] + bb[o0 + oo], 0.0f);
    }
    __syncthreads();
    for (int u = t; u < 128 * 64; u += 256) wsm[u] = w2[u];
    if (t < 128) bb[t] = b2[t];
    __syncthreads();
    {
        int k = t >> 3, o0 = (t & 7) * 16;
        float acc[16];
#pragma unroll
        for (int oo = 0; oo < 16; ++oo) acc[oo] = 0.0f;
        for (int c = 0; c < 64; ++c) {
            float xv = h2[k][c];
#pragma unroll
            for (int oo = 0; oo < 16; ++oo) acc[oo] += xv * wsm[(o0 + oo) * 64 + c];
        }
        float g0 = gxs[k][0], g1 = gxs[k][1], g2 = gxs[k][2];
        int row = k * SS + s;
#pragma unroll
        for (int oo = 0; oo < 16; ++oo) {
            int o = o0 + oo;
            float v = fmaxf(acc[oo] + bb[o], 0.0f);
            v += g0 * wpos[o * 3 + 0] + g1 * wpos[o * 3 + 1] + g2 * wpos[o * 3 + 2];
            P[row * CC + o] = v;
        }
    }
}

// ---------------- QKV via MFMA: D[m][n] = sum_k P[m][k] * w[k][n], Wt pre-transposed ----------------
__global__ __launch_bounds__(256) void qkv_kernel(const float* __restrict__ P,
                                                  const ushort* __restrict__ Wt,  // 3x [n][k] bf16
                                                  ushort* __restrict__ Qg,
                                                  ushort* __restrict__ Kg,
                                                  ushort* __restrict__ Vg) {
    __shared__ ushort Pb[64 * 136];
    __shared__ ushort Wb[128 * 136];
    int t = threadIdx.x;
    int w = t >> 6, l = t & 63, g = l >> 4, c = l & 15;
    int r0 = blockIdx.x * 64;
    for (int idx = t; idx < 64 * 32; idx += 256) {
        int r = idx >> 5, c4 = (idx & 31) * 4;
        float4 v = *(const float4*)(P + (r0 + r) * CC + c4);
        ushort4 u4 = make_ushort4(f2bf(v.x), f2bf(v.y), f2bf(v.z), f2bf(v.w));
        *(ushort4*)&Pb[r * 136 + c4] = u4;
    }
    ushort* om[3] = {Qg, Kg, Vg};
    for (int m = 0; m < 3; ++m) {
        __syncthreads();   // Pb ready (m=0) / Wb drained (m>0)
        for (int idx = t; idx < 128 * 16; idx += 256) {
            int r = idx >> 4, ch = idx & 15;
            *(int4*)&Wb[r * 136 + ch * 8] = *(const int4*)&Wt[m * CC * CC + r * CC + ch * 8];
        }
        __syncthreads();
        bf16x8 a[4];
#pragma unroll
        for (int ck = 0; ck < 4; ++ck)
            a[ck] = *(const bf16x8*)&Pb[(w * 16 + c) * 136 + ck * 32 + g * 8];
        float s = (m == 0) ? SCALEQ : 1.0f;
        ushort* og = om[m];
#pragma unroll
        for (int n0 = 0; n0 < 8; ++n0) {
            f32x4 acc = (f32x4){0.f, 0.f, 0.f, 0.f};
#pragma unroll
            for (int ck = 0; ck < 4; ++ck) {
                bf16x8 bv = *(const bf16x8*)&Wb[(n0 * 16 + c) * 136 + ck * 32 + g * 8];
                acc = __builtin_amdgcn_mfma_f32_16x16x32_bf16(a[ck], bv, acc, 0, 0, 0);
            }
#pragma unroll
            for (int r = 0; r < 4; ++r)
                og[(r0 + w * 16 + 4 * g + r) * CC + n0 * 16 + c] = f2bf(acc[r] * s);
        }
    }
}

// ---------------- Flash attention, bf16 MFMA 16x16x32, one batch; O -> bf16 ----------------
__global__ __launch_bounds__(256) void attn_kernel(const ushort* __restrict__ Qg,
                                                   const ushort* __restrict__ Kg,
                                                   const ushort* __restrict__ Vg,
                                                   ushort* __restrict__ Og) {
    __shared__ ushort Qs[64 * 136];
    __shared__ ushort Ks[32 * 136];
    __shared__ ushort Vt[128 * 40];    // V transposed: Vt[d][k]
    __shared__ ushort Ps[4 * 16 * 40]; // per-warp P tile [q 16][k 32]
    int t = threadIdx.x;
    int w = t >> 6, l = t & 63, g = l >> 4, c = l & 15;
    int head = blockIdx.x >> 4, qt = blockIdx.x & 15;
    int r0 = head * SS + qt * 64;
    int hr = head * SS;
    for (int idx = t; idx < 64 * 16; idx += 256) {
        int r = idx >> 4, ch = idx & 15;
        *(int4*)&Qs[r * 136 + ch * 8] = *(const int4*)&Qg[(r0 + r) * CC + ch * 8];
    }
    f32x4 oacc[8];
    float mrun[4], lrun[4];
#pragma unroll
    for (int d = 0; d < 8; ++d) oacc[d] = (f32x4){0.f, 0.f, 0.f, 0.f};
#pragma unroll
    for (int r = 0; r < 4; ++r) { mrun[r] = -1e30f; lrun[r] = 0.0f; }
    ushort* psw = &Ps[w * 16 * 40];

    for (int kt = 0; kt < 32; ++kt) {
        __syncthreads();
        for (int idx = t; idx < 32 * 16; idx += 256) {
            int r = idx >> 4, ch = idx & 15;
            *(int4*)&Ks[r * 136 + ch * 8] = *(const int4*)&Kg[(hr + kt * 32 + r) * CC + ch * 8];
        }
#pragma unroll
        for (int h = 0; h < 2; ++h) {
            int r = t & 31, cg = (t >> 5) + h * 8;
            int4 vv = *(const int4*)&Vg[(hr + kt * 32 + r) * CC + cg * 8];
            const ushort* us = (const ushort*)&vv;
#pragma unroll
            for (int e = 0; e < 8; ++e) Vt[(cg * 8 + e) * 40 + r] = us[e];
        }
        __syncthreads();
        f32x4 sc0 = (f32x4){0.f, 0.f, 0.f, 0.f};
        f32x4 sc1 = (f32x4){0.f, 0.f, 0.f, 0.f};
#pragma unroll
        for (int ck = 0; ck < 4; ++ck) {
            bf16x8 a  = *(const bf16x8*)&Qs[(w * 16 + c) * 136 + ck * 32 + g * 8];
            bf16x8 b0 = *(const bf16x8*)&Ks[c * 136 + ck * 32 + g * 8];
            bf16x8 b1 = *(const bf16x8*)&Ks[(16 + c) * 136 + ck * 32 + g * 8];
            sc0 = __builtin_amdgcn_mfma_f32_16x16x32_bf16(a, b0, sc0, 0, 0, 0);
            sc1 = __builtin_amdgcn_mfma_f32_16x16x32_bf16(a, b1, sc1, 0, 0, 0);
        }
#pragma unroll
        for (int r = 0; r < 4; ++r) {
            float mx = fmaxf(sc0[r], sc1[r]);
#pragma unroll
            for (int off = 1; off < 16; off <<= 1) mx = fmaxf(mx, __shfl_xor(mx, off));
            float mn = fmaxf(mrun[r], mx);
            float f = __expf(mrun[r] - mn);
            mrun[r] = mn;
            float p0 = __expf(sc0[r] - mn);
            float p1 = __expf(sc1[r] - mn);
            psw[(4 * g + r) * 40 + c]      = f2bf(p0);
            psw[(4 * g + r) * 40 + 16 + c] = f2bf(p1);
            float ps = p0 + p1;
#pragma unroll
            for (int off = 1; off < 16; off <<= 1) ps += __shfl_xor(ps, off);
            lrun[r] = lrun[r] * f + ps;
#pragma unroll
            for (int d = 0; d < 8; ++d) oacc[d][r] *= f;
        }
        bf16x8 pa = *(const bf16x8*)&psw[c * 40 + g * 8];
#pragma unroll
        for (int d = 0; d < 8; ++d) {
            bf16x8 bv = *(const bf16x8*)&Vt[(d * 16 + c) * 40 + g * 8];
            oacc[d] = __builtin_amdgcn_mfma_f32_16x16x32_bf16(pa, bv, oacc[d], 0, 0, 0);
        }
    }
#pragma unroll
    for (int r = 0; r < 4; ++r) {
        float inv = 1.0f / lrun[r];
        int row = r0 + w * 16 + 4 * g + r;
#pragma unroll
        for (int d = 0; d < 8; ++d)
            Og[row * CC + d * 16 + c] = f2bf(oacc[d][r] * inv);
    }
}

// ---------------- P += O @ wo via MFMA (O bf16, Wt pre-transposed), one batch ----------------
__global__ __launch_bounds__(256) void wo_kernel(const ushort* __restrict__ O,
                                                 const ushort* __restrict__ Wot,  // [n][k] bf16
                                                 float* __restrict__ P) {
    __shared__ ushort Ob[64 * 136];
    __shared__ ushort Wb[128 * 136];
    int t = threadIdx.x;
    int w = t >> 6, l = t & 63, g = l >> 4, c = l & 15;
    int r0 = blockIdx.x * 64;
    for (int idx = t; idx < 64 * 16; idx += 256) {
        int r = idx >> 4, ch = idx & 15;
        *(int4*)&Ob[r * 136 + ch * 8] = *(const int4*)&O[(r0 + r) * CC + ch * 8];
    }
    for (int idx = t; idx < 128 * 16; idx += 256) {
        int r = idx >> 4, ch = idx & 15;
        *(int4*)&Wb[r * 136 + ch * 8] = *(const int4*)&Wot[r * CC + ch * 8];
    }
    __syncthreads();
    bf16x8 a[4];
#pragma unroll
    for (int ck = 0; ck < 4; ++ck)
        a[ck] = *(const bf16x8*)&Ob[(w * 16 + c) * 136 + ck * 32 + g * 8];
#pragma unroll
    for (int n0 = 0; n0 < 8; ++n0) {
        f32x4 acc = (f32x4){0.f, 0.f, 0.f, 0.f};
#pragma unroll
        for (int ck = 0; ck < 4; ++ck) {
            bf16x8 bv = *(const bf16x8*)&Wb[(n0 * 16 + c) * 136 + ck * 32 + g * 8];
            acc = __builtin_amdgcn_mfma_f32_16x16x32_bf16(a[ck], bv, acc, 0, 0, 0);
        }
#pragma unroll
        for (int r = 0; r < 4; ++r) {
            float* dst = P + (r0 + w * 16 + 4 * g + r) * CC + n0 * 16 + c;
            *dst += acc[r];
        }
    }
}

// ---------------- maxpool over k -> out_b (C,S), one batch ----------------
__global__ __launch_bounds__(256) void maxpool_kernel(const float* __restrict__ P,
                                                      float* __restrict__ out_b) {
    int s = blockIdx.x * 2 + (threadIdx.x >> 7);
    int c = threadIdx.x & 127;
    const float* base = P + s * CC + c;
    float v = -1e30f;
#pragma unroll 4
    for (int k = 0; k < KS; ++k) v = fmaxf(v, base[k * SS * CC]);
    out_b[c * SS + s] = v;
}

extern "C" void kernel_launch(void* const* d_in, const int* in_sizes, int n_in,
                              void* d_out, int out_size, void* d_ws, size_t ws_size,
                              hipStream_t stream) {
    const float* xyz  = (const float*)d_in[0];
    const float* pts  = (const float*)d_in[1];
    const float* w0   = (const float*)d_in[2];
    const float* b0   = (const float*)d_in[3];
    const float* w1   = (const float*)d_in[4];
    const float* b1   = (const float*)d_in[5];
    const float* w2   = (const float*)d_in[6];
    const float* b2   = (const float*)d_in[7];
    const float* wq   = (const float*)d_in[8];
    const float* wk   = (const float*)d_in[9];
    const float* wv   = (const float*)d_in[10];
    const float* wo   = (const float*)d_in[11];
    const float* wpos = (const float*)d_in[12];
    float* out = (float*)d_out;
    char* ws = (char*)d_ws;
    float*  nx   = (float*)(ws + WS_NX);
    int*    gidx = (int*)(ws + WS_GIDX);
    float*  P    = (float*)(ws + WS_P);
    ushort* Qb   = (ushort*)(ws + WS_QB);
    ushort* Kb   = (ushort*)(ws + WS_KB);
    ushort* Vb   = (ushort*)(ws + WS_VB);
    ushort* Ob   = (ushort*)(ws + WS_OB);
    ushort* Wt   = (ushort*)(ws + WS_WT);   // [wq|wk|wv|wo] transposed bf16

    prep_weights_kernel<<<4, 256, 0, stream>>>(wq, wk, wv, wo, Wt);
    fps_kernel<<<NB, 1024, 0, stream>>>(xyz, out, nx);
    ballquery_kernel<<<(NB * SS) / 4, 256, 0, stream>>>(xyz, nx, gidx);
    for (int b = 0; b < NB; ++b) {
        group_mlp_kernel<<<SS, 256, 0, stream>>>(xyz, pts, nx, gidx,
                                                 w0, b0, w1, b1, w2, b2, wpos, P, b);
        qkv_kernel<<<(KS * SS) / 64, 256, 0, stream>>>(P, Wt, Qb, Kb, Vb);
        attn_kernel<<<KS * (SS / 64), 256, 0, stream>>>(Qb, Kb, Vb, Ob);
        wo_kernel<<<(KS * SS) / 64, 256, 0, stream>>>(Ob, Wt + 3 * CC * CC, P);
        maxpool_kernel<<<SS / 2, 256, 0, stream>>>(P, out + NB * 3 * SS + b * CC * SS);
    }
}

// Round 13
// 2248.832 us; speedup vs baseline: 4.6031x; 1.1707x over previous
//
#include <hip/hip_runtime.h>
#include <hip/hip_bf16.h>
#include <math.h>

#define NB 4
#define NPTS 4096
#define SS 1024
#define KS 32
#define DIN 64
#define CC 128

typedef __attribute__((ext_vector_type(8))) short bf16x8;
typedef __attribute__((ext_vector_type(4))) float f32x4;

#define SCALEQ 0.08838834764831845f

// ws layout (bytes)
#define WS_NX   0u                       // float[4*1024*3]
#define WS_GIDX 49152u                   // int[4*1024*32]
#define WS_P    (1u<<20)                 // float[32768*128] one batch (16MB)
#define WS_QB   (WS_P  + 16777216u)      // bf16 [32768*128] (8MB)
#define WS_KB   (WS_QB + 8388608u)
#define WS_VB   (WS_KB + 8388608u)
#define WS_OB   (WS_VB + 8388608u)       // bf16 [32768*128] (8MB)
#define WS_WT   (WS_OB + 8388608u)       // bf16 4x[128*128] transposed weights (128KB)

static __device__ __forceinline__ ushort f2bf(float x) {
    __hip_bfloat16 h = __float2bfloat16(x);
    return *(ushort*)&h;
}

// ---------------- prep: Wt[n][k] = bf16(w[k][n]) for wq,wk,wv,wo ----------------
__global__ __launch_bounds__(256) void prep_weights_kernel(const float* __restrict__ wq,
                                                           const float* __restrict__ wk,
                                                           const float* __restrict__ wv,
                                                           const float* __restrict__ wo,
                                                           ushort* __restrict__ dst) {
    const float* src = (blockIdx.x == 0) ? wq : (blockIdx.x == 1) ? wk
                      : (blockIdx.x == 2) ? wv : wo;
    ushort* d = dst + blockIdx.x * CC * CC;
    for (int idx = threadIdx.x; idx < CC * CC; idx += 256) {
        int k = idx >> 7, n = idx & 127;          // coalesced read along n
        d[n * CC + k] = f2bf(src[k * CC + n]);    // transposed write
    }
}

// ---------------- FPS: 1 block/batch, 256 thr, points in registers, 1 barrier/iter ----------------
// r11 redesign: per-iter cost was ~3600cyc (2 barriers + serial t0-reduce + LDS point reads).
// Now: points live in 48 VGPRs/thread (never change); every lane redundantly reduces the
// 4 wave-partials (shfl_xor over redv[l&3]) so `far` needs no bcast; redv double-buffered
// by parity so ONE barrier orders write-after-read. Argmax semantics bit-identical.
__global__ __launch_bounds__(256) void fps_kernel(const float* __restrict__ xyz,
                                                  float* __restrict__ out_newxyz,
                                                  float* __restrict__ ws_nx) {
    int b = blockIdx.x;
    const float* xb = xyz + b * 3 * NPTS;
    __shared__ float xs[NPTS], ys[NPTS], zs[NPTS];
    __shared__ float redv[2][4];
    __shared__ int   redi[2][4];
    int t = threadIdx.x;
    int w = t >> 6, l = t & 63;
    for (int n = t; n < NPTS; n += 256) {
        xs[n] = xb[n]; ys[n] = xb[NPTS + n]; zs[n] = xb[2 * NPTS + n];
    }
    __syncthreads();
    float px[16], py[16], pz[16], dist[16];
#pragma unroll
    for (int j = 0; j < 16; ++j) {
        int n = j * 256 + t;
        px[j] = xs[n]; py[j] = ys[n]; pz[j] = zs[n];
        dist[j] = 1e10f;
    }
    int far = 0;
    for (int i = 0; i < SS; ++i) {
        float cx = xs[far], cy = ys[far], cz = zs[far];
        if (t == 0) {
            out_newxyz[b * 3 * SS + 0 * SS + i] = cx;
            out_newxyz[b * 3 * SS + 1 * SS + i] = cy;
            out_newxyz[b * 3 * SS + 2 * SS + i] = cz;
            ws_nx[(b * SS + i) * 3 + 0] = cx;
            ws_nx[(b * SS + i) * 3 + 1] = cy;
            ws_nx[(b * SS + i) * 3 + 2] = cz;
        }
        float bestv = -1.0f; int bestn = 0;
#pragma unroll
        for (int j = 0; j < 16; ++j) {
            float dx = __fsub_rn(px[j], cx);
            float dy = __fsub_rn(py[j], cy);
            float dz = __fsub_rn(pz[j], cz);
            float d = __fadd_rn(__fadd_rn(__fmul_rn(dx, dx), __fmul_rn(dy, dy)), __fmul_rn(dz, dz));
            float dd = fminf(dist[j], d);
            dist[j] = dd;
            if (dd > bestv) { bestv = dd; bestn = j * 256 + t; }  // j asc -> first max kept
        }
#pragma unroll
        for (int off = 32; off >= 1; off >>= 1) {
            float ov = __shfl_down(bestv, off);
            int   on = __shfl_down(bestn, off);
            if (ov > bestv || (ov == bestv && on < bestn)) { bestv = ov; bestn = on; }
        }
        int sl = i & 1;
        if (l == 0) { redv[sl][w] = bestv; redi[sl][w] = bestn; }
        __syncthreads();
        float bv = redv[sl][l & 3]; int bn = redi[sl][l & 3];
#pragma unroll
        for (int off = 1; off < 4; off <<= 1) {
            float ov = __shfl_xor(bv, off);
            int   on = __shfl_xor(bn, off);
            if (ov > bv || (ov == bv && on < bn)) { bv = ov; bn = on; }
        }
        far = bn;   // every lane computed the identical global argmax
    }
}

// ---------------- Ball query: one wave per (b,s), exact-match sq ----------------
__global__ __launch_bounds__(256) void ballquery_kernel(const float* __restrict__ xyz,
                                                        const float* __restrict__ nx,
                                                        int* __restrict__ gidx) {
    int wid = blockIdx.x * 4 + (threadIdx.x >> 6);   // b*SS + s
    int l = threadIdx.x & 63;
    int b = wid >> 10;
    const float* xb = xyz + b * 3 * NPTS;
    float qx = nx[wid * 3 + 0];
    float qy = nx[wid * 3 + 1];
    float qz = nx[wid * 3 + 2];
    float a = __fadd_rn(__fadd_rn(__fmul_rn(qx, qx), __fmul_rn(qy, qy)), __fmul_rn(qz, qz));
    int* g = gidx + wid * KS;
    int cnt = 0, first = -1;
    for (int base = 0; base < NPTS; base += 64) {
        int n = base + l;
        float x = xb[n], y = xb[NPTS + n], z = xb[2 * NPTS + n];
        float bn = __fadd_rn(__fadd_rn(__fmul_rn(x, x), __fmul_rn(y, y)), __fmul_rn(z, z));
        float dt = __fadd_rn(__fadd_rn(__fmul_rn(qx, x), __fmul_rn(qy, y)), __fmul_rn(qz, z));
        float sq = __fadd_rn(__fsub_rn(a, __fmul_rn(2.0f, dt)), bn);
        bool qual = (sq <= 0.04f);
        unsigned long long m = __ballot(qual);
        if (qual) {
            int pos = __popcll(m & ((1ull << l) - 1ull));
            int slot = cnt + pos;
            if (slot < KS) g[slot] = n;
        }
        if (first < 0 && m != 0ull) first = base + __ffsll((long long)m) - 1;
        cnt += __popcll(m);
        if (cnt >= KS) break;
    }
    if (cnt < KS) {
        int f = (first >= 0) ? first : 0;
        int slot = cnt + l;
        if (slot < KS) g[slot] = f;
    }
}

// ---------------- Gather + MLP(67->64->64->128, relu) + pos-enc -> P_b (K,S,C) ----------------
__global__ __launch_bounds__(256) void group_mlp_kernel(
        const float* __restrict__ xyz, const float* __restrict__ pts,
        const float* __restrict__ nx, const int* __restrict__ gidx,
        const float* __restrict__ w0, const float* __restrict__ b0,
        const float* __restrict__ w1, const float* __restrict__ b1,
        const float* __restrict__ w2, const float* __restrict__ b2,
        const float* __restrict__ wpos, float* __restrict__ P, int b) {
    int s = blockIdx.x;
    int t = threadIdx.x;
    __shared__ float xin[32][68];
    __shared__ float gxs[32][4];
    __shared__ float h1[32][64];
    __shared__ float h2[32][64];
    __shared__ float wsm[8192];
    __shared__ float bb[128];
    __shared__ int idxs[32];
    int bs = b * SS + s;
    if (t < 32) idxs[t] = gidx[bs * KS + t];
    __syncthreads();
    float qx = nx[bs * 3 + 0], qy = nx[bs * 3 + 1], qz = nx[bs * 3 + 2];
    {
        int k = t >> 3, c0 = t & 7;
        int n = idxs[k];
        for (int c = c0; c < 67; c += 8) {
            float v;
            if (c < 3) {
                v = xyz[(b * 3 + c) * NPTS + n];
                gxs[k][c] = v;
                v = v - (c == 0 ? qx : (c == 1 ? qy : qz));
            } else {
                v = pts[(b * DIN + (c - 3)) * NPTS + n];
            }
            xin[k][c] = v;
        }
    }
    for (int u = t; u < 64 * 67; u += 256) wsm[u] = w0[u];
    if (t < 64) bb[t] = b0[t];
    __syncthreads();
    {
        int k = t >> 3, o0 = (t & 7) * 8;
        float acc[8] = {0,0,0,0,0,0,0,0};
        for (int c = 0; c < 67; ++c) {
            float xv = xin[k][c];
#pragma unroll
            for (int oo = 0; oo < 8; ++oo) acc[oo] += xv * wsm[(o0 + oo) * 67 + c];
        }
#pragma unroll
        for (int oo = 0; oo < 8; ++oo) h1[k][o0 + oo] = fmaxf(acc[oo] + bb[o0 + oo], 0.0f);
    }
    __syncthreads();
    for (int u = t; u < 64 * 64; u += 256) wsm[u] = w1[u];
    if (t < 64) bb[t] = b1[t];
    __syncthreads();
    {
        int k = t >> 3, o0 = (t & 7) * 8;
        float acc[8] = {0,0,0,0,0,0,0,0};
        for (int c = 0; c < 64; ++c) {
            float xv = h1[k][c];
#pragma unroll
            for (int oo = 0; oo < 8; ++oo) acc[oo] += xv * wsm[(o0 + oo) * 64 + c];
        }
#pragma unroll
        for (int oo = 0; oo < 8; ++oo) h2[k][o0 + oo] = fmaxf(acc[oo] + bb[o0 + oo], 0.0f);
    }
    __syncthreads();
    for (int u = t; u < 128 * 64; u += 256) wsm[u] = w2[u];
    if (t < 128) bb[t] = b2[t];
    __syncthreads();
    {
        int k = t >> 3, o0 = (t & 7) * 16;
        float acc[16];
#pragma unroll
        for (int oo = 0; oo < 16; ++oo) acc[oo] = 0.0f;
        for (int c = 0; c < 64; ++c) {
            float xv = h2[k][c];
#pragma unroll
            for (int oo = 0; oo < 16; ++oo) acc[oo] += xv * wsm[(o0 + oo) * 64 + c];
        }
        float g0 = gxs[k][0], g1 = gxs[k][1], g2 = gxs[k][2];
        int row = k * SS + s;
#pragma unroll
        for (int oo = 0; oo < 16; ++oo) {
            int o = o0 + oo;
            float v = fmaxf(acc[oo] + bb[o], 0.0f);
            v += g0 * wpos[o * 3 + 0] + g1 * wpos[o * 3 + 1] + g2 * wpos[o * 3 + 2];
            P[row * CC + o] = v;
        }
    }
}

// ---------------- QKV via MFMA: D[m][n] = sum_k P[m][k] * w[k][n], Wt pre-transposed ----------------
__global__ __launch_bounds__(256) void qkv_kernel(const float* __restrict__ P,
                                                  const ushort* __restrict__ Wt,  // 3x [n][k] bf16
                                                  ushort* __restrict__ Qg,
                                                  ushort* __restrict__ Kg,
                                                  ushort* __restrict__ Vg) {
    __shared__ ushort Pb[64 * 136];
    __shared__ ushort Wb[128 * 136];
    int t = threadIdx.x;
    int w = t >> 6, l = t & 63, g = l >> 4, c = l & 15;
    int r0 = blockIdx.x * 64;
    for (int idx = t; idx < 64 * 32; idx += 256) {
        int r = idx >> 5, c4 = (idx & 31) * 4;
        float4 v = *(const float4*)(P + (r0 + r) * CC + c4);
        ushort4 u4 = make_ushort4(f2bf(v.x), f2bf(v.y), f2bf(v.z), f2bf(v.w));
        *(ushort4*)&Pb[r * 136 + c4] = u4;
    }
    ushort* om[3] = {Qg, Kg, Vg};
    for (int m = 0; m < 3; ++m) {
        __syncthreads();   // Pb ready (m=0) / Wb drained (m>0)
        for (int idx = t; idx < 128 * 16; idx += 256) {
            int r = idx >> 4, ch = idx & 15;
            *(int4*)&Wb[r * 136 + ch * 8] = *(const int4*)&Wt[m * CC * CC + r * CC + ch * 8];
        }
        __syncthreads();
        bf16x8 a[4];
#pragma unroll
        for (int ck = 0; ck < 4; ++ck)
            a[ck] = *(const bf16x8*)&Pb[(w * 16 + c) * 136 + ck * 32 + g * 8];
        float s = (m == 0) ? SCALEQ : 1.0f;
        ushort* og = om[m];
#pragma unroll
        for (int n0 = 0; n0 < 8; ++n0) {
            f32x4 acc = (f32x4){0.f, 0.f, 0.f, 0.f};
#pragma unroll
            for (int ck = 0; ck < 4; ++ck) {
                bf16x8 bv = *(const bf16x8*)&Wb[(n0 * 16 + c) * 136 + ck * 32 + g * 8];
                acc = __builtin_amdgcn_mfma_f32_16x16x32_bf16(a[ck], bv, acc, 0, 0, 0);
            }
#pragma unroll
            for (int r = 0; r < 4; ++r)
                og[(r0 + w * 16 + 4 * g + r) * CC + n0 * 16 + c] = f2bf(acc[r] * s);
        }
    }
}

// ---------------- Flash attention, bf16 MFMA 16x16x32, one batch; O -> bf16 ----------------
__global__ __launch_bounds__(256) void attn_kernel(const ushort* __restrict__ Qg,
                                                   const ushort* __restrict__ Kg,
                                                   const ushort* __restrict__ Vg,
                                                   ushort* __restrict__ Og) {
    __shared__ ushort Qs[64 * 136];
    __shared__ ushort Ks[32 * 136];
    __shared__ ushort Vt[128 * 40];    // V transposed: Vt[d][k]
    __shared__ ushort Ps[4 * 16 * 40]; // per-warp P tile [q 16][k 32]
    int t = threadIdx.x;
    int w = t >> 6, l = t & 63, g = l >> 4, c = l & 15;
    int head = blockIdx.x >> 4, qt = blockIdx.x & 15;
    int r0 = head * SS + qt * 64;
    int hr = head * SS;
    for (int idx = t; idx < 64 * 16; idx += 256) {
        int r = idx >> 4, ch = idx & 15;
        *(int4*)&Qs[r * 136 + ch * 8] = *(const int4*)&Qg[(r0 + r) * CC + ch * 8];
    }
    f32x4 oacc[8];
    float mrun[4], lrun[4];
#pragma unroll
    for (int d = 0; d < 8; ++d) oacc[d] = (f32x4){0.f, 0.f, 0.f, 0.f};
#pragma unroll
    for (int r = 0; r < 4; ++r) { mrun[r] = -1e30f; lrun[r] = 0.0f; }
    ushort* psw = &Ps[w * 16 * 40];

    for (int kt = 0; kt < 32; ++kt) {
        __syncthreads();
        for (int idx = t; idx < 32 * 16; idx += 256) {
            int r = idx >> 4, ch = idx & 15;
            *(int4*)&Ks[r * 136 + ch * 8] = *(const int4*)&Kg[(hr + kt * 32 + r) * CC + ch * 8];
        }
#pragma unroll
        for (int h = 0; h < 2; ++h) {
            int r = t & 31, cg = (t >> 5) + h * 8;
            int4 vv = *(const int4*)&Vg[(hr + kt * 32 + r) * CC + cg * 8];
            const ushort* us = (const ushort*)&vv;
#pragma unroll
            for (int e = 0; e < 8; ++e) Vt[(cg * 8 + e) * 40 + r] = us[e];
        }
        __syncthreads();
        f32x4 sc0 = (f32x4){0.f, 0.f, 0.f, 0.f};
        f32x4 sc1 = (f32x4){0.f, 0.f, 0.f, 0.f};
#pragma unroll
        for (int ck = 0; ck < 4; ++ck) {
            bf16x8 a  = *(const bf16x8*)&Qs[(w * 16 + c) * 136 + ck * 32 + g * 8];
            bf16x8 b0 = *(const bf16x8*)&Ks[c * 136 + ck * 32 + g * 8];
            bf16x8 b1 = *(const bf16x8*)&Ks[(16 + c) * 136 + ck * 32 + g * 8];
            sc0 = __builtin_amdgcn_mfma_f32_16x16x32_bf16(a, b0, sc0, 0, 0, 0);
            sc1 = __builtin_amdgcn_mfma_f32_16x16x32_bf16(a, b1, sc1, 0, 0, 0);
        }
#pragma unroll
        for (int r = 0; r < 4; ++r) {
            float mx = fmaxf(sc0[r], sc1[r]);
#pragma unroll
            for (int off = 1; off < 16; off <<= 1) mx = fmaxf(mx, __shfl_xor(mx, off));
            float mn = fmaxf(mrun[r], mx);
            float f = __expf(mrun[r] - mn);
            mrun[r] = mn;
            float p0 = __expf(sc0[r] - mn);
            float p1 = __expf(sc1[r] - mn);
            psw[(4 * g + r) * 40 + c]      = f2bf(p0);
            psw[(4 * g + r) * 40 + 16 + c] = f2bf(p1);
            float ps = p0 + p1;
#pragma unroll
            for (int off = 1; off < 16; off <<= 1) ps += __shfl_xor(ps, off);
            lrun[r] = lrun[r] * f + ps;
#pragma unroll
            for (int d = 0; d < 8; ++d) oacc[d][r] *= f;
        }
        bf16x8 pa = *(const bf16x8*)&psw[c * 40 + g * 8];
#pragma unroll
        for (int d = 0; d < 8; ++d) {
            bf16x8 bv = *(const bf16x8*)&Vt[(d * 16 + c) * 40 + g * 8];
            oacc[d] = __builtin_amdgcn_mfma_f32_16x16x32_bf16(pa, bv, oacc[d], 0, 0, 0);
        }
    }
#pragma unroll
    for (int r = 0; r < 4; ++r) {
        float inv = 1.0f / lrun[r];
        int row = r0 + w * 16 + 4 * g + r;
#pragma unroll
        for (int d = 0; d < 8; ++d)
            Og[row * CC + d * 16 + c] = f2bf(oacc[d][r] * inv);
    }
}

// ---------------- P += O @ wo via MFMA (O bf16, Wt pre-transposed), one batch ----------------
__global__ __launch_bounds__(256) void wo_kernel(const ushort* __restrict__ O,
                                                 const ushort* __restrict__ Wot,  // [n][k] bf16
                                                 float* __restrict__ P) {
    __shared__ ushort Ob[64 * 136];
    __shared__ ushort Wb[128 * 136];
    int t = threadIdx.x;
    int w = t >> 6, l = t & 63, g = l >> 4, c = l & 15;
    int r0 = blockIdx.x * 64;
    for (int idx = t; idx < 64 * 16; idx += 256) {
        int r = idx >> 4, ch = idx & 15;
        *(int4*)&Ob[r * 136 + ch * 8] = *(const int4*)&O[(r0 + r) * CC + ch * 8];
    }
    for (int idx = t; idx < 128 * 16; idx += 256) {
        int r = idx >> 4, ch = idx & 15;
        *(int4*)&Wb[r * 136 + ch * 8] = *(const int4*)&Wot[r * CC + ch * 8];
    }
    __syncthreads();
    bf16x8 a[4];
#pragma unroll
    for (int ck = 0; ck < 4; ++ck)
        a[ck] = *(const bf16x8*)&Ob[(w * 16 + c) * 136 + ck * 32 + g * 8];
#pragma unroll
    for (int n0 = 0; n0 < 8; ++n0) {
        f32x4 acc = (f32x4){0.f, 0.f, 0.f, 0.f};
#pragma unroll
        for (int ck = 0; ck < 4; ++ck) {
            bf16x8 bv = *(const bf16x8*)&Wb[(n0 * 16 + c) * 136 + ck * 32 + g * 8];
            acc = __builtin_amdgcn_mfma_f32_16x16x32_bf16(a[ck], bv, acc, 0, 0, 0);
        }
#pragma unroll
        for (int r = 0; r < 4; ++r) {
            float* dst = P + (r0 + w * 16 + 4 * g + r) * CC + n0 * 16 + c;
            *dst += acc[r];
        }
    }
}

// ---------------- maxpool over k -> out_b (C,S), one batch ----------------
__global__ __launch_bounds__(256) void maxpool_kernel(const float* __restrict__ P,
                                                      float* __restrict__ out_b) {
    int s = blockIdx.x * 2 + (threadIdx.x >> 7);
    int c = threadIdx.x & 127;
    const float* base = P + s * CC + c;
    float v = -1e30f;
#pragma unroll 4
    for (int k = 0; k < KS; ++k) v = fmaxf(v, base[k * SS * CC]);
    out_b[c * SS + s] = v;
}

extern "C" void kernel_launch(void* const* d_in, const int* in_sizes, int n_in,
                              void* d_out, int out_size, void* d_ws, size_t ws_size,
                              hipStream_t stream) {
    const float* xyz  = (const float*)d_in[0];
    const float* pts  = (const float*)d_in[1];
    const float* w0   = (const float*)d_in[2];
    const float* b0   = (const float*)d_in[3];
    const float* w1   = (const float*)d_in[4];
    const float* b1   = (const float*)d_in[5];
    const float* w2   = (const float*)d_in[6];
    const float* b2   = (const float*)d_in[7];
    const float* wq   = (const float*)d_in[8];
    const float* wk   = (const float*)d_in[9];
    const float* wv   = (const float*)d_in[10];
    const float* wo   = (const float*)d_in[11];
    const float* wpos = (const float*)d_in[12];
    float* out = (float*)d_out;
    char* ws = (char*)d_ws;
    float*  nx   = (float*)(ws + WS_NX);
    int*    gidx = (int*)(ws + WS_GIDX);
    float*  P    = (float*)(ws + WS_P);
    ushort* Qb   = (ushort*)(ws + WS_QB);
    ushort* Kb   = (ushort*)(ws + WS_KB);
    ushort* Vb   = (ushort*)(ws + WS_VB);
    ushort* Ob   = (ushort*)(ws + WS_OB);
    ushort* Wt   = (ushort*)(ws + WS_WT);   // [wq|wk|wv|wo] transposed bf16

    prep_weights_kernel<<<4, 256, 0, stream>>>(wq, wk, wv, wo, Wt);
    fps_kernel<<<NB, 256, 0, stream>>>(xyz, out, nx);
    ballquery_kernel<<<(NB * SS) / 4, 256, 0, stream>>>(xyz, nx, gidx);
    for (int b = 0; b < NB; ++b) {
        group_mlp_kernel<<<SS, 256, 0, stream>>>(xyz, pts, nx, gidx,
                                                 w0, b0, w1, b1, w2, b2, wpos, P, b);
        qkv_kernel<<<(KS * SS) / 64, 256, 0, stream>>>(P, Wt, Qb, Kb, Vb);
        attn_kernel<<<KS * (SS / 64), 256, 0, stream>>>(Qb, Kb, Vb, Ob);
        wo_kernel<<<(KS * SS) / 64, 256, 0, stream>>>(Ob, Wt + 3 * CC * CC, P);
        maxpool_kernel<<<SS / 2, 256, 0, stream>>>(P, out + NB * 3 * SS + b * CC * SS);
    }
}

// Round 15
// 1691.399 us; speedup vs baseline: 6.1202x; 1.3296x over previous
//
#include <hip/hip_runtime.h>
#include <hip/hip_bf16.h>
#include <math.h>

#define NB 4
#define NPTS 4096
#define SS 1024
#define KS 32
#define DIN 64
#define CC 128

typedef __attribute__((ext_vector_type(8))) short bf16x8;
typedef __attribute__((ext_vector_type(4))) float f32x4;
typedef unsigned long long ull;

#define SCALEQ 0.08838834764831845f

// ws layout (bytes)
#define WS_NX   0u                       // float[4*1024*3]
#define WS_GIDX 49152u                   // int[4*1024*32]
#define WS_P    (1u<<20)                 // float[32768*128] one batch (16MB)
#define WS_QB   (WS_P  + 16777216u)      // bf16 [32768*128] (8MB)
#define WS_KB   (WS_QB + 8388608u)
#define WS_VB   (WS_KB + 8388608u)
#define WS_OB   (WS_VB + 8388608u)       // bf16 [32768*128] (8MB)
#define WS_WT   (WS_OB + 8388608u)       // bf16 4x[128*128] transposed weights (128KB)

static __device__ __forceinline__ ushort f2bf(float x) {
    __hip_bfloat16 h = __float2bfloat16(x);
    return *(ushort*)&h;
}

// u64-max of packed (distbits<<32 | ~index): exact (max dist, tie -> min index)
static __device__ __forceinline__ ull kmax(ull a, ull b) { return a > b ? a : b; }

// one DPP step of the packed-key max reduce (all-VALU; masked rows get key 0 = identity)
#define DPP_KSTEP(k, CTRL, RM)                                                        \
    {                                                                                 \
        unsigned hi2 = (unsigned)__builtin_amdgcn_update_dpp(0, (int)(unsigned)((k) >> 32), CTRL, RM, 0xf, false); \
        unsigned lo2 = (unsigned)__builtin_amdgcn_update_dpp(0, (int)(unsigned)(k), CTRL, RM, 0xf, false);         \
        ull k2 = ((ull)hi2 << 32) | lo2;                                              \
        k = kmax(k, k2);                                                              \
    }

// ---------------- prep: Wt[n][k] = bf16(w[k][n]) for wq,wk,wv,wo ----------------
__global__ __launch_bounds__(256) void prep_weights_kernel(const float* __restrict__ wq,
                                                           const float* __restrict__ wk,
                                                           const float* __restrict__ wv,
                                                           const float* __restrict__ wo,
                                                           ushort* __restrict__ dst) {
    const float* src = (blockIdx.x == 0) ? wq : (blockIdx.x == 1) ? wk
                      : (blockIdx.x == 2) ? wv : wo;
    ushort* d = dst + blockIdx.x * CC * CC;
    for (int idx = threadIdx.x; idx < CC * CC; idx += 256) {
        int k = idx >> 7, n = idx & 127;          // coalesced read along n
        d[n * CC + k] = f2bf(src[k * CC + n]);    // transposed write
    }
}

// ---------------- FPS v3: packed u64 keys + all-VALU DPP reduce, 1 barrier/iter ----------------
// r13 diagnosis: __shfl_* = ds_bpermute (~100cyc LDS latency) x8 dependent levels dominated.
// Now: per-lane best as u64 key (distbits<<32 | ~n, exact numpy tie-break); wave reduce via
// DPP row_ror 1/2/4/8 + row_bcast15/31 (VALU speed) -> lane63; cross-wave via 4-key LDS
// broadcast read merged by EVERY lane (no second broadcast). Parity double-buffer, 1 barrier.
__global__ __launch_bounds__(256) void fps_kernel(const float* __restrict__ xyz,
                                                  float* __restrict__ out_newxyz,
                                                  float* __restrict__ ws_nx) {
    int b = blockIdx.x;
    const float* xb = xyz + b * 3 * NPTS;
    __shared__ float xs[NPTS], ys[NPTS], zs[NPTS];
    __shared__ ull kbuf[2][4];
    int t = threadIdx.x;
    int w = t >> 6, l = t & 63;
    for (int n = t; n < NPTS; n += 256) {
        xs[n] = xb[n]; ys[n] = xb[NPTS + n]; zs[n] = xb[2 * NPTS + n];
    }
    __syncthreads();
    float px[16], py[16], pz[16], dist[16];
#pragma unroll
    for (int j = 0; j < 16; ++j) {
        int n = j * 256 + t;
        px[j] = xs[n]; py[j] = ys[n]; pz[j] = zs[n];
        dist[j] = 1e10f;
    }
    int far = 0;
    for (int i = 0; i < SS; ++i) {
        float cx = xs[far], cy = ys[far], cz = zs[far];
        if (t == 0) {
            out_newxyz[b * 3 * SS + 0 * SS + i] = cx;
            out_newxyz[b * 3 * SS + 1 * SS + i] = cy;
            out_newxyz[b * 3 * SS + 2 * SS + i] = cz;
            ws_nx[(b * SS + i) * 3 + 0] = cx;
            ws_nx[(b * SS + i) * 3 + 1] = cy;
            ws_nx[(b * SS + i) * 3 + 2] = cz;
        }
        // per-lane best over 16 pts: 4 sub-chains (depth 4) + merge (depth 2)
        ull ks[4] = {0ull, 0ull, 0ull, 0ull};
#pragma unroll
        for (int j = 0; j < 16; ++j) {
            float dx = __fsub_rn(px[j], cx);
            float dy = __fsub_rn(py[j], cy);
            float dz = __fsub_rn(pz[j], cz);
            float d = __fadd_rn(__fadd_rn(__fmul_rn(dx, dx), __fmul_rn(dy, dy)), __fmul_rn(dz, dz));
            float dd = fminf(dist[j], d);
            dist[j] = dd;
            unsigned vb = __float_as_uint(dd);
            ull key = ((ull)vb << 32) | (ull)(0xFFFFFFFFu - (unsigned)(j * 256 + t));
            ks[j & 3] = kmax(ks[j & 3], key);
        }
        ull k = kmax(kmax(ks[0], ks[1]), kmax(ks[2], ks[3]));
        // wave reduce, all-VALU DPP: rows then cross-row broadcasts -> lane 63
        DPP_KSTEP(k, 0x121, 0xf);   // row_ror:1
        DPP_KSTEP(k, 0x122, 0xf);   // row_ror:2
        DPP_KSTEP(k, 0x124, 0xf);   // row_ror:4
        DPP_KSTEP(k, 0x128, 0xf);   // row_ror:8  -> every lane has its 16-row max
        DPP_KSTEP(k, 0x142, 0xa);   // row_bcast15 -> rows 1,3 = pairwise max
        DPP_KSTEP(k, 0x143, 0xc);   // row_bcast31 -> rows 2,3 = wave max (lane 63 valid)
        int sl = i & 1;
        if (l == 63) kbuf[sl][w] = k;
        __syncthreads();
        // every lane merges the 4 wave keys (same-address LDS reads = broadcast)
        ull g0 = kbuf[sl][0], g1 = kbuf[sl][1], g2 = kbuf[sl][2], g3 = kbuf[sl][3];
        ull kg = kmax(kmax(g0, g1), kmax(g2, g3));
        far = (int)(0xFFFFFFFFu - (unsigned)kg);
    }
}

// ---------------- Ball query: one wave per (b,s), exact-match sq ----------------
__global__ __launch_bounds__(256) void ballquery_kernel(const float* __restrict__ xyz,
                                                        const float* __restrict__ nx,
                                                        int* __restrict__ gidx) {
    int wid = blockIdx.x * 4 + (threadIdx.x >> 6);   // b*SS + s
    int l = threadIdx.x & 63;
    int b = wid >> 10;
    const float* xb = xyz + b * 3 * NPTS;
    float qx = nx[wid * 3 + 0];
    float qy = nx[wid * 3 + 1];
    float qz = nx[wid * 3 + 2];
    float a = __fadd_rn(__fadd_rn(__fmul_rn(qx, qx), __fmul_rn(qy, qy)), __fmul_rn(qz, qz));
    int* g = gidx + wid * KS;
    int cnt = 0, first = -1;
    for (int base = 0; base < NPTS; base += 64) {
        int n = base + l;
        float x = xb[n], y = xb[NPTS + n], z = xb[2 * NPTS + n];
        float bn = __fadd_rn(__fadd_rn(__fmul_rn(x, x), __fmul_rn(y, y)), __fmul_rn(z, z));
        float dt = __fadd_rn(__fadd_rn(__fmul_rn(qx, x), __fmul_rn(qy, y)), __fmul_rn(qz, z));
        float sq = __fadd_rn(__fsub_rn(a, __fmul_rn(2.0f, dt)), bn);
        bool qual = (sq <= 0.04f);
        unsigned long long m = __ballot(qual);
        if (qual) {
            int pos = __popcll(m & ((1ull << l) - 1ull));
            int slot = cnt + pos;
            if (slot < KS) g[slot] = n;
        }
        if (first < 0 && m != 0ull) first = base + __ffsll((long long)m) - 1;
        cnt += __popcll(m);
        if (cnt >= KS) break;
    }
    if (cnt < KS) {
        int f = (first >= 0) ? first : 0;
        int slot = cnt + l;
        if (slot < KS) g[slot] = f;
    }
}

// ---------------- Gather + MLP(67->64->64->128, relu) + pos-enc -> P_b (K,S,C) ----------------
__global__ __launch_bounds__(256) void group_mlp_kernel(
        const float* __restrict__ xyz, const float* __restrict__ pts,
        const float* __restrict__ nx, const int* __restrict__ gidx,
        const float* __restrict__ w0, const float* __restrict__ b0,
        const float* __restrict__ w1, const float* __restrict__ b1,
        const float* __restrict__ w2, const float* __restrict__ b2,
        const float* __restrict__ wpos, float* __restrict__ P, int b) {
    int s = blockIdx.x;
    int t = threadIdx.x;
    __shared__ float xin[32][68];
    __shared__ float gxs[32][4];
    __shared__ float h1[32][64];
    __shared__ float h2[32][64];
    __shared__ float wsm[8192];
    __shared__ float bb[128];
    __shared__ int idxs[32];
    int bs = b * SS + s;
    if (t < 32) idxs[t] = gidx[bs * KS + t];
    __syncthreads();
    float qx = nx[bs * 3 + 0], qy = nx[bs * 3 + 1], qz = nx[bs * 3 + 2];
    {
        int k = t >> 3, c0 = t & 7;
        int n = idxs[k];
        for (int c = c0; c < 67; c += 8) {
            float v;
            if (c < 3) {
                v = xyz[(b * 3 + c) * NPTS + n];
                gxs[k][c] = v;
                v = v - (c == 0 ? qx : (c == 1 ? qy : qz));
            } else {
                v = pts[(b * DIN + (c - 3)) * NPTS + n];
            }
            xin[k][c] = v;
        }
    }
    for (int u = t; u < 64 * 67; u += 256) wsm[u] = w0[u];
    if (t < 64) bb[t] = b0[t];
    __syncthreads();
    {
        int k = t >> 3, o0 = (t & 7) * 8;
        float acc[8] = {0,0,0,0,0,0,0,0};
        for (int c = 0; c < 67; ++c) {
            float xv = xin[k][c];
#pragma unroll
            for (int oo = 0; oo < 8; ++oo) acc[oo] += xv * wsm[(o0 + oo) * 67 + c];
        }
#pragma unroll
        for (int oo = 0; oo < 8; ++oo) h1[k][o0 + oo] = fmaxf(acc[oo] + bb[o0 + oo], 0.0f);
    }
    __syncthreads();
    for (int u = t; u < 64 * 64; u += 256) wsm[u] = w1[u];
    if (t < 64) bb[t] = b1[t];
    __syncthreads();
    {
        int k = t >> 3, o0 = (t & 7) * 8;
        float acc[8] = {0,0,0,0,0,0,0,0};
        for (int c = 0; c < 64; ++c) {
            float xv = h1[k][c];
#pragma unroll
            for (int oo = 0; oo < 8; ++oo) acc[oo] += xv * wsm[(o0 + oo) * 64 + c];
        }
#pragma unroll
        for (int oo = 0; oo < 8; ++oo) h2[k][o0 + oo] = fmaxf(acc[oo] + bb[o0 + oo], 0.0f);
    }
    __syncthreads();
    for (int u = t; u < 128 * 64; u += 256) wsm[u] = w2[u];
    if (t < 128) bb[t] = b2[t];
    __syncthreads();
    {
        int k = t >> 3, o0 = (t & 7) * 16;
        float acc[16];
#pragma unroll
        for (int oo = 0; oo < 16; ++oo) acc[oo] = 0.0f;
        for (int c = 0; c < 64; ++c) {
            float xv = h2[k][c];
#pragma unroll
            for (int oo = 0; oo < 16; ++oo) acc[oo] += xv * wsm[(o0 + oo) * 64 + c];
        }
        float g0 = gxs[k][0], g1 = gxs[k][1], g2 = gxs[k][2];
        int row = k * SS + s;
#pragma unroll
        for (int oo = 0; oo < 16; ++oo) {
            int o = o0 + oo;
            float v = fmaxf(acc[oo] + bb[o], 0.0f);
            v += g0 * wpos[o * 3 + 0] + g1 * wpos[o * 3 + 1] + g2 * wpos[o * 3 + 2];
            P[row * CC + o] = v;
        }
    }
}

// ---------------- QKV via MFMA: D[m][n] = sum_k P[m][k] * w[k][n], Wt pre-transposed ----------------
__global__ __launch_bounds__(256) void qkv_kernel(const float* __restrict__ P,
                                                  const ushort* __restrict__ Wt,  // 3x [n][k] bf16
                                                  ushort* __restrict__ Qg,
                                                  ushort* __restrict__ Kg,
                                                  ushort* __restrict__ Vg) {
    __shared__ ushort Pb[64 * 136];
    __shared__ ushort Wb[128 * 136];
    int t = threadIdx.x;
    int w = t >> 6, l = t & 63, g = l >> 4, c = l & 15;
    int r0 = blockIdx.x * 64;
    for (int idx = t; idx < 64 * 32; idx += 256) {
        int r = idx >> 5, c4 = (idx & 31) * 4;
        float4 v = *(const float4*)(P + (r0 + r) * CC + c4);
        ushort4 u4 = make_ushort4(f2bf(v.x), f2bf(v.y), f2bf(v.z), f2bf(v.w));
        *(ushort4*)&Pb[r * 136 + c4] = u4;
    }
    ushort* om[3] = {Qg, Kg, Vg};
    for (int m = 0; m < 3; ++m) {
        __syncthreads();   // Pb ready (m=0) / Wb drained (m>0)
        for (int idx = t; idx < 128 * 16; idx += 256) {
            int r = idx >> 4, ch = idx & 15;
            *(int4*)&Wb[r * 136 + ch * 8] = *(const int4*)&Wt[m * CC * CC + r * CC + ch * 8];
        }
        __syncthreads();
        bf16x8 a[4];
#pragma unroll
        for (int ck = 0; ck < 4; ++ck)
            a[ck] = *(const bf16x8*)&Pb[(w * 16 + c) * 136 + ck * 32 + g * 8];
        float s = (m == 0) ? SCALEQ : 1.0f;
        ushort* og = om[m];
#pragma unroll
        for (int n0 = 0; n0 < 8; ++n0) {
            f32x4 acc = (f32x4){0.f, 0.f, 0.f, 0.f};
#pragma unroll
            for (int ck = 0; ck < 4; ++ck) {
                bf16x8 bv = *(const bf16x8*)&Wb[(n0 * 16 + c) * 136 + ck * 32 + g * 8];
                acc = __builtin_amdgcn_mfma_f32_16x16x32_bf16(a[ck], bv, acc, 0, 0, 0);
            }
#pragma unroll
            for (int r = 0; r < 4; ++r)
                og[(r0 + w * 16 + 4 * g + r) * CC + n0 * 16 + c] = f2bf(acc[r] * s);
        }
    }
}

// ---------------- Flash attention, bf16 MFMA 16x16x32, one batch; O -> bf16 ----------------
__global__ __launch_bounds__(256) void attn_kernel(const ushort* __restrict__ Qg,
                                                   const ushort* __restrict__ Kg,
                                                   const ushort* __restrict__ Vg,
                                                   ushort* __restrict__ Og) {
    __shared__ ushort Qs[64 * 136];
    __shared__ ushort Ks[32 * 136];
    __shared__ ushort Vt[128 * 40];    // V transposed: Vt[d][k]
    __shared__ ushort Ps[4 * 16 * 40]; // per-warp P tile [q 16][k 32]
    int t = threadIdx.x;
    int w = t >> 6, l = t & 63, g = l >> 4, c = l & 15;
    int head = blockIdx.x >> 4, qt = blockIdx.x & 15;
    int r0 = head * SS + qt * 64;
    int hr = head * SS;
    for (int idx = t; idx < 64 * 16; idx += 256) {
        int r = idx >> 4, ch = idx & 15;
        *(int4*)&Qs[r * 136 + ch * 8] = *(const int4*)&Qg[(r0 + r) * CC + ch * 8];
    }
    f32x4 oacc[8];
    float mrun[4], lrun[4];
#pragma unroll
    for (int d = 0; d < 8; ++d) oacc[d] = (f32x4){0.f, 0.f, 0.f, 0.f};
#pragma unroll
    for (int r = 0; r < 4; ++r) { mrun[r] = -1e30f; lrun[r] = 0.0f; }
    ushort* psw = &Ps[w * 16 * 40];

    for (int kt = 0; kt < 32; ++kt) {
        __syncthreads();
        for (int idx = t; idx < 32 * 16; idx += 256) {
            int r = idx >> 4, ch = idx & 15;
            *(int4*)&Ks[r * 136 + ch * 8] = *(const int4*)&Kg[(hr + kt * 32 + r) * CC + ch * 8];
        }
#pragma unroll
        for (int h = 0; h < 2; ++h) {
            int r = t & 31, cg = (t >> 5) + h * 8;
            int4 vv = *(const int4*)&Vg[(hr + kt * 32 + r) * CC + cg * 8];
            const ushort* us = (const ushort*)&vv;
#pragma unroll
            for (int e = 0; e < 8; ++e) Vt[(cg * 8 + e) * 40 + r] = us[e];
        }
        __syncthreads();
        f32x4 sc0 = (f32x4){0.f, 0.f, 0.f, 0.f};
        f32x4 sc1 = (f32x4){0.f, 0.f, 0.f, 0.f};
#pragma unroll
        for (int ck = 0; ck < 4; ++ck) {
            bf16x8 a  = *(const bf16x8*)&Qs[(w * 16 + c) * 136 + ck * 32 + g * 8];
            bf16x8 b0 = *(const bf16x8*)&Ks[c * 136 + ck * 32 + g * 8];
            bf16x8 b1 = *(const bf16x8*)&Ks[(16 + c) * 136 + ck * 32 + g * 8];
            sc0 = __builtin_amdgcn_mfma_f32_16x16x32_bf16(a, b0, sc0, 0, 0, 0);
            sc1 = __builtin_amdgcn_mfma_f32_16x16x32_bf16(a, b1, sc1, 0, 0, 0);
        }
#pragma unroll
        for (int r = 0; r < 4; ++r) {
            float mx = fmaxf(sc0[r], sc1[r]);
#pragma unroll
            for (int off = 1; off < 16; off <<= 1) mx = fmaxf(mx, __shfl_xor(mx, off));
            float mn = fmaxf(mrun[r], mx);
            float f = __expf(mrun[r] - mn);
            mrun[r] = mn;
            float p0 = __expf(sc0[r] - mn);
            float p1 = __expf(sc1[r] - mn);
            psw[(4 * g + r) * 40 + c]      = f2bf(p0);
            psw[(4 * g + r) * 40 + 16 + c] = f2bf(p1);
            float ps = p0 + p1;
#pragma unroll
            for (int off = 1; off < 16; off <<= 1) ps += __shfl_xor(ps, off);
            lrun[r] = lrun[r] * f + ps;
#pragma unroll
            for (int d = 0; d < 8; ++d) oacc[d][r] *= f;
        }
        bf16x8 pa = *(const bf16x8*)&psw[c * 40 + g * 8];
#pragma unroll
        for (int d = 0; d < 8; ++d) {
            bf16x8 bv = *(const bf16x8*)&Vt[(d * 16 + c) * 40 + g * 8];
            oacc[d] = __builtin_amdgcn_mfma_f32_16x16x32_bf16(pa, bv, oacc[d], 0, 0, 0);
        }
    }
#pragma unroll
    for (int r = 0; r < 4; ++r) {
        float inv = 1.0f / lrun[r];
        int row = r0 + w * 16 + 4 * g + r;
#pragma unroll
        for (int d = 0; d < 8; ++d)
            Og[row * CC + d * 16 + c] = f2bf(oacc[d][r] * inv);
    }
}

// ---------------- P += O @ wo via MFMA (O bf16, Wt pre-transposed), one batch ----------------
__global__ __launch_bounds__(256) void wo_kernel(const ushort* __restrict__ O,
                                                 const ushort* __restrict__ Wot,  // [n][k] bf16
                                                 float* __restrict__ P) {
    __shared__ ushort Ob[64 * 136];
    __shared__ ushort Wb[128 * 136];
    int t = threadIdx.x;
    int w = t >> 6, l = t & 63, g = l >> 4, c = l & 15;
    int r0 = blockIdx.x * 64;
    for (int idx = t; idx < 64 * 16; idx += 256) {
        int r = idx >> 4, ch = idx & 15;
        *(int4*)&Ob[r * 136 + ch * 8] = *(const int4*)&O[(r0 + r) * CC + ch * 8];
    }
    for (int idx = t; idx < 128 * 16; idx += 256) {
        int r = idx >> 4, ch = idx & 15;
        *(int4*)&Wb[r * 136 + ch * 8] = *(const int4*)&Wot[r * CC + ch * 8];
    }
    __syncthreads();
    bf16x8 a[4];
#pragma unroll
    for (int ck = 0; ck < 4; ++ck)
        a[ck] = *(const bf16x8*)&Ob[(w * 16 + c) * 136 + ck * 32 + g * 8];
#pragma unroll
    for (int n0 = 0; n0 < 8; ++n0) {
        f32x4 acc = (f32x4){0.f, 0.f, 0.f, 0.f};
#pragma unroll
        for (int ck = 0; ck < 4; ++ck) {
            bf16x8 bv = *(const bf16x8*)&Wb[(n0 * 16 + c) * 136 + ck * 32 + g * 8];
            acc = __builtin_amdgcn_mfma_f32_16x16x32_bf16(a[ck], bv, acc, 0, 0, 0);
        }
#pragma unroll
        for (int r = 0; r < 4; ++r) {
            float* dst = P + (r0 + w * 16 + 4 * g + r) * CC + n0 * 16 + c;
            *dst += acc[r];
        }
    }
}

// ---------------- maxpool over k -> out_b (C,S), one batch ----------------
__global__ __launch_bounds__(256) void maxpool_kernel(const float* __restrict__ P,
                                                      float* __restrict__ out_b) {
    int s = blockIdx.x * 2 + (threadIdx.x >> 7);
    int c = threadIdx.x & 127;
    const float* base = P + s * CC + c;
    float v = -1e30f;
#pragma unroll 4
    for (int k = 0; k < KS; ++k) v = fmaxf(v, base[k * SS * CC]);
    out_b[c * SS + s] = v;
}

extern "C" void kernel_launch(void* const* d_in, const int* in_sizes, int n_in,
                              void* d_out, int out_size, void* d_ws, size_t ws_size,
                              hipStream_t stream) {
    const float* xyz  = (const float*)d_in[0];
    const float* pts  = (const float*)d_in[1];
    const float* w0   = (const float*)d_in[2];
    const float* b0   = (const float*)d_in[3];
    const float* w1   = (const float*)d_in[4];
    const float* b1   = (const float*)d_in[5];
    const float* w2   = (const float*)d_in[6];
    const float* b2   = (const float*)d_in[7];
    const float* wq   = (const float*)d_in[8];
    const float* wk   = (const float*)d_in[9];
    const float* wv   = (const float*)d_in[10];
    const float* wo   = (const float*)d_in[11];
    const float* wpos = (const float*)d_in[12];
    float* out = (float*)d_out;
    char* ws = (char*)d_ws;
    float*  nx   = (float*)(ws + WS_NX);
    int*    gidx = (int*)(ws + WS_GIDX);
    float*  P    = (float*)(ws + WS_P);
    ushort* Qb   = (ushort*)(ws + WS_QB);
    ushort* Kb   = (ushort*)(ws + WS_KB);
    ushort* Vb   = (ushort*)(ws + WS_VB);
    ushort* Ob   = (ushort*)(ws + WS_OB);
    ushort* Wt   = (ushort*)(ws + WS_WT);   // [wq|wk|wv|wo] transposed bf16

    prep_weights_kernel<<<4, 256, 0, stream>>>(wq, wk, wv, wo, Wt);
    fps_kernel<<<NB, 256, 0, stream>>>(xyz, out, nx);
    ballquery_kernel<<<(NB * SS) / 4, 256, 0, stream>>>(xyz, nx, gidx);
    for (int b = 0; b < NB; ++b) {
        group_mlp_kernel<<<SS, 256, 0, stream>>>(xyz, pts, nx, gidx,
                                                 w0, b0, w1, b1, w2, b2, wpos, P, b);
        qkv_kernel<<<(KS * SS) / 64, 256, 0, stream>>>(P, Wt, Qb, Kb, Vb);
        attn_kernel<<<KS * (SS / 64), 256, 0, stream>>>(Qb, Kb, Vb, Ob);
        wo_kernel<<<(KS * SS) / 64, 256, 0, stream>>>(Ob, Wt + 3 * CC * CC, P);
        maxpool_kernel<<<SS / 2, 256, 0, stream>>>(P, out + NB * 3 * SS + b * CC * SS);
    }
}